// Round 2
// baseline (2977.392 us; speedup 1.0000x reference)
//
#include <hip/hip_runtime.h>
#include <hip/hip_bf16.h>
#include <stdint.h>

// CriticGNN: two GraphConv branches + MLP head.
// Trick: aggregate AFTER the 128->16 transform (segment_sum is linear),
// so edge traffic is 16 floats/edge instead of 128.
// Round 1: runtime dtype detection (bf16 vs f32 device buffers) — the NaN in
// round 0 is only explicable by reading f32 data as bf16 pairs, but the test
// label says bf16; a flag kernel resolves it and both load paths are compiled.

#define F_IN 128

__device__ __forceinline__ float bf2f(unsigned short u) {
    union { unsigned int i; float f; } v; v.i = ((unsigned int)u) << 16; return v.f;
}
__device__ __forceinline__ float bflo(unsigned int u) {
    union { unsigned int i; float f; } v; v.i = u << 16; return v.f;
}
__device__ __forceinline__ float bfhi(unsigned int u) {
    union { unsigned int i; float f; } v; v.i = u & 0xffff0000u; return v.f;
}
__device__ __forceinline__ unsigned short f2bf(float f) {
    union { float f; unsigned int i; } v; v.f = f;
    unsigned int u = v.i;
    unsigned int r = (u + 0x7fffu + ((u >> 16) & 1u)) >> 16;  // RNE
    return (unsigned short)r;
}
// load float from buffer that is either f32 (isf32=1) or bf16 (isf32=0)
__device__ __forceinline__ float ldf(const void* p, int isf32, size_t i) {
    return isf32 ? ((const float*)p)[i] : bf2f(((const unsigned short*)p)[i]);
}

// Decide dtype: bf16 N(0,1) data has exponent field ~[117,131]; f32 data read
// as uint16 pairs has ~45% random exponents (low halves = mantissa bits).
__global__ __launch_bounds__(256) void k_detect(
    const unsigned short* __restrict__ x, int nProbe, int* __restrict__ flag)
{
    __shared__ int cnt;
    if (threadIdx.x == 0) cnt = 0;
    __syncthreads();
    int bad = 0;
    for (int i = threadIdx.x; i < nProbe; i += 256) {
        unsigned e = (x[i] >> 7) & 0xFFu;
        if (e >= 140u) bad++;
    }
    atomicAdd(&cnt, bad);
    __syncthreads();
    if (threadIdx.x == 0) *flag = (cnt > nProbe / 16) ? 1 : 0;
}

// acc1 = x @ w_self + bias ; n1 = x @ w_nbr   (x: [N,128], W: [128,16])
__global__ __launch_bounds__(256) void k_transform1(
    const void* __restrict__ x,
    const void* __restrict__ w_self,
    const void* __restrict__ w_nbr,
    const void* __restrict__ bias,
    float* __restrict__ acc1, float* __restrict__ n1, int n,
    const int* __restrict__ flag)
{
    const int isf32 = *flag;
    __shared__ float Wl[F_IN][32];  // cols 0..15 = w_self, 16..31 = w_nbr
    for (int idx = threadIdx.x; idx < F_IN * 32; idx += 256) {
        int k = idx >> 5, j = idx & 31;
        Wl[k][j] = (j < 16) ? ldf(w_self, isf32, k * 16 + j)
                            : ldf(w_nbr, isf32, k * 16 + (j - 16));
    }
    __syncthreads();
    int node = blockIdx.x * 256 + threadIdx.x;
    if (node >= n) return;
    float acc[32];
#pragma unroll
    for (int j = 0; j < 16; ++j) acc[j] = ldf(bias, isf32, j);
#pragma unroll
    for (int j = 16; j < 32; ++j) acc[j] = 0.f;

    if (isf32) {
        const float4* xrow = (const float4*)((const float*)x + (size_t)node * F_IN);
        for (int kk = 0; kk < 32; ++kk) {
            float4 q = xrow[kk];
            float xs[4] = {q.x, q.y, q.z, q.w};
            int kbase = kk * 4;
#pragma unroll
            for (int h = 0; h < 4; ++h) {
                float xv = xs[h];
                const float* wrow = &Wl[kbase + h][0];
#pragma unroll
                for (int j = 0; j < 32; ++j) acc[j] += xv * wrow[j];
            }
        }
    } else {
        const uint4* xrow = (const uint4*)((const unsigned short*)x + (size_t)node * F_IN);
        for (int kk = 0; kk < 16; ++kk) {   // 8 bf16 per iteration
            uint4 q = xrow[kk];
            float xs[8] = {bflo(q.x), bfhi(q.x), bflo(q.y), bfhi(q.y),
                           bflo(q.z), bfhi(q.z), bflo(q.w), bfhi(q.w)};
            int kbase = kk * 8;
#pragma unroll
            for (int h = 0; h < 8; ++h) {
                float xv = xs[h];
                const float* wrow = &Wl[kbase + h][0];
#pragma unroll
                for (int j = 0; j < 32; ++j) acc[j] += xv * wrow[j];
            }
        }
    }
    float4* a4 = (float4*)(acc1 + (size_t)node * 16);
    float4* n4 = (float4*)(n1 + (size_t)node * 16);
#pragma unroll
    for (int t = 0; t < 4; ++t) {
        a4[t] = make_float4(acc[4 * t], acc[4 * t + 1], acc[4 * t + 2], acc[4 * t + 3]);
        n4[t] = make_float4(acc[16 + 4 * t], acc[17 + 4 * t], acc[18 + 4 * t], acc[19 + 4 * t]);
    }
}

// acc[dst] += val[src] over 16-float rows; 4 threads per edge (float4 each)
__global__ __launch_bounds__(256) void k_scatter16(
    const int* __restrict__ esrc, const int* __restrict__ edst,
    const float* __restrict__ val, float* __restrict__ acc, int nE)
{
    int t = blockIdx.x * 256 + threadIdx.x;
    int e = t >> 2;
    if (e >= nE) return;
    int c = (t & 3) << 2;
    int s = esrc[e], d = edst[e];
    const float4 v = *(const float4*)(val + ((size_t)s << 4) + c);
    float* a = acc + ((size_t)d << 4) + c;
    unsafeAtomicAdd(a + 0, v.x);
    unsafeAtomicAdd(a + 1, v.y);
    unsafeAtomicAdd(a + 2, v.z);
    unsafeAtomicAdd(a + 3, v.w);
}

// p1 = relu(acc1); acc2 = p1 @ w2s + b2; zero acc1 (becomes agg2 target)
__global__ __launch_bounds__(256) void k_layer2a(
    float* __restrict__ acc1, float* __restrict__ p1, float* __restrict__ acc2,
    const void* __restrict__ w2s, const void* __restrict__ b2, int n,
    const int* __restrict__ flag)
{
    const int isf32 = *flag;
    __shared__ float Ws[16][50];
    __shared__ float Bs[50];
    for (int idx = threadIdx.x; idx < 800; idx += 256)
        Ws[idx / 50][idx % 50] = ldf(w2s, isf32, idx);
    if (threadIdx.x < 50) Bs[threadIdx.x] = ldf(b2, isf32, threadIdx.x);
    __syncthreads();
    int node = blockIdx.x * 256 + threadIdx.x;
    if (node >= n) return;
    float p[16];
    float4* row = (float4*)(acc1 + (size_t)node * 16);
#pragma unroll
    for (int t = 0; t < 4; ++t) {
        float4 v = row[t];
        p[4 * t] = fmaxf(v.x, 0.f); p[4 * t + 1] = fmaxf(v.y, 0.f);
        p[4 * t + 2] = fmaxf(v.z, 0.f); p[4 * t + 3] = fmaxf(v.w, 0.f);
        row[t] = make_float4(0.f, 0.f, 0.f, 0.f);
    }
    float4* pout = (float4*)(p1 + (size_t)node * 16);
#pragma unroll
    for (int t = 0; t < 4; ++t)
        pout[t] = make_float4(p[4 * t], p[4 * t + 1], p[4 * t + 2], p[4 * t + 3]);
    float acc[50];
#pragma unroll
    for (int j = 0; j < 50; ++j) acc[j] = Bs[j];
#pragma unroll
    for (int k = 0; k < 16; ++k) {
        float pv = p[k];
#pragma unroll
        for (int j = 0; j < 50; ++j) acc[j] += pv * Ws[k][j];
    }
    float* o = acc2 + (size_t)node * 50;
#pragma unroll
    for (int j = 0; j < 50; ++j) o[j] = acc[j];
}

// mol[:, colOff..colOff+50) = acc2 + agg2 @ w2n
__global__ __launch_bounds__(256) void k_layer2b(
    const float* __restrict__ agg2, const float* __restrict__ acc2,
    float* __restrict__ mol, const void* __restrict__ w2n, int colOff, int n,
    const int* __restrict__ flag)
{
    const int isf32 = *flag;
    __shared__ float Ws[16][50];
    for (int idx = threadIdx.x; idx < 800; idx += 256)
        Ws[idx / 50][idx % 50] = ldf(w2n, isf32, idx);
    __syncthreads();
    int node = blockIdx.x * 256 + threadIdx.x;
    if (node >= n) return;
    float g[16];
    const float4* grow = (const float4*)(agg2 + (size_t)node * 16);
#pragma unroll
    for (int t = 0; t < 4; ++t) {
        float4 v = grow[t];
        g[4 * t] = v.x; g[4 * t + 1] = v.y; g[4 * t + 2] = v.z; g[4 * t + 3] = v.w;
    }
    float acc[50];
    const float* arow = acc2 + (size_t)node * 50;
#pragma unroll
    for (int j = 0; j < 50; ++j) acc[j] = arow[j];
#pragma unroll
    for (int k = 0; k < 16; ++k) {
        float gv = g[k];
#pragma unroll
        for (int j = 0; j < 50; ++j) acc[j] += gv * Ws[k][j];
    }
    float* o = mol + (size_t)node * 100 + colOff;
#pragma unroll
    for (int j = 0; j < 50; ++j) o[j] = acc[j];
}

// head: fp = relu(mol@w_in+b_in); h = relu([fp,action]@w_hid+b_hid); out = h@w_out+b_out
__global__ __launch_bounds__(256) void k_head(
    const float* __restrict__ mol, const void* __restrict__ action,
    const void* __restrict__ w_in, const void* __restrict__ b_in,
    const void* __restrict__ w_hid, const void* __restrict__ b_hid,
    const void* __restrict__ w_out, const void* __restrict__ b_out,
    void* __restrict__ out, int n, const int* __restrict__ flag)
{
    const int isf32 = *flag;
    __shared__ float Win[100 * 60];
    __shared__ float Whid[70 * 10];
    __shared__ float Bin[60], Bhid[10], Wout[10];
    __shared__ float Bout;
    for (int idx = threadIdx.x; idx < 6000; idx += 256) Win[idx] = ldf(w_in, isf32, idx);
    for (int idx = threadIdx.x; idx < 700; idx += 256) Whid[idx] = ldf(w_hid, isf32, idx);
    if (threadIdx.x < 60) Bin[threadIdx.x] = ldf(b_in, isf32, threadIdx.x);
    if (threadIdx.x < 10) {
        Bhid[threadIdx.x] = ldf(b_hid, isf32, threadIdx.x);
        Wout[threadIdx.x] = ldf(w_out, isf32, threadIdx.x);
    }
    if (threadIdx.x == 0) Bout = ldf(b_out, isf32, 0);
    __syncthreads();
    int node = blockIdx.x * 256 + threadIdx.x;
    if (node >= n) return;
    float fp[60];
#pragma unroll
    for (int j = 0; j < 60; ++j) fp[j] = Bin[j];
    const float* mrow = mol + (size_t)node * 100;
    for (int k = 0; k < 100; ++k) {
        float m = mrow[k];
        const float* w = &Win[k * 60];
#pragma unroll
        for (int j = 0; j < 60; ++j) fp[j] += m * w[j];
    }
    float h[10];
#pragma unroll
    for (int j = 0; j < 10; ++j) h[j] = Bhid[j];
#pragma unroll
    for (int k = 0; k < 60; ++k) {
        float v = fmaxf(fp[k], 0.f);
        const float* w = &Whid[k * 10];
#pragma unroll
        for (int j = 0; j < 10; ++j) h[j] += v * w[j];
    }
#pragma unroll
    for (int k = 0; k < 10; ++k) {
        float v = ldf(action, isf32, (size_t)node * 10 + k);
        const float* w = &Whid[(60 + k) * 10];
#pragma unroll
        for (int j = 0; j < 10; ++j) h[j] += v * w[j];
    }
    float o = Bout;
#pragma unroll
    for (int j = 0; j < 10; ++j) o += fmaxf(h[j], 0.f) * Wout[j];
    if (isf32) ((float*)out)[node] = o;
    else       ((unsigned short*)out)[node] = f2bf(o);
}

extern "C" void kernel_launch(void* const* d_in, const int* in_sizes, int n_in,
                              void* d_out, int out_size, void* d_ws, size_t ws_size,
                              hipStream_t stream)
{
    const void* px   = d_in[0];
    const int*  pe   = (const int*)d_in[1];
    const void* lx   = d_in[2];
    const int*  le   = (const int*)d_in[3];
    const void* act  = d_in[4];
    const void* wp1s = d_in[5];
    const void* wp1n = d_in[6];
    const void* bp1  = d_in[7];
    const void* wp2s = d_in[8];
    const void* wp2n = d_in[9];
    const void* bp2  = d_in[10];
    const void* wl1s = d_in[11];
    const void* wl1n = d_in[12];
    const void* bl1  = d_in[13];
    const void* wl2s = d_in[14];
    const void* wl2n = d_in[15];
    const void* bl2  = d_in[16];
    const void* w_in  = d_in[17];
    const void* b_in  = d_in[18];
    const void* w_hid = d_in[19];
    const void* b_hid = d_in[20];
    const void* w_out = d_in[21];
    const void* b_out = d_in[22];

    const int N = in_sizes[0] / F_IN;
    const int E = in_sizes[1] / 2;

    // workspace: flag (256B pad) | acc1[16N] | n1[16N] | acc2[50N] | mol[100N]
    int* flag   = (int*)d_ws;
    float* base = (float*)((char*)d_ws + 256);
    float* acc1 = base;
    float* n1   = acc1 + (size_t)N * 16;
    float* acc2 = n1 + (size_t)N * 16;
    float* mol  = acc2 + (size_t)N * 50;

    const int nb = (N + 255) / 256;
    const int sb = (E * 4 + 255) / 256;

    k_detect<<<1, 256, 0, stream>>>((const unsigned short*)px, 4096, flag);

    // protein branch -> mol[:, 0:50]
    k_transform1<<<nb, 256, 0, stream>>>(px, wp1s, wp1n, bp1, acc1, n1, N, flag);
    k_scatter16<<<sb, 256, 0, stream>>>(pe, pe + E, n1, acc1, E);
    k_layer2a<<<nb, 256, 0, stream>>>(acc1, n1, acc2, wp2s, bp2, N, flag);
    k_scatter16<<<sb, 256, 0, stream>>>(pe, pe + E, n1, acc1, E);
    k_layer2b<<<nb, 256, 0, stream>>>(acc1, acc2, mol, wp2n, 0, N, flag);

    // ligand branch -> mol[:, 50:100]
    k_transform1<<<nb, 256, 0, stream>>>(lx, wl1s, wl1n, bl1, acc1, n1, N, flag);
    k_scatter16<<<sb, 256, 0, stream>>>(le, le + E, n1, acc1, E);
    k_layer2a<<<nb, 256, 0, stream>>>(acc1, n1, acc2, wl2s, bl2, N, flag);
    k_scatter16<<<sb, 256, 0, stream>>>(le, le + E, n1, acc1, E);
    k_layer2b<<<nb, 256, 0, stream>>>(acc1, acc2, mol, wl2n, 50, N, flag);

    // head
    k_head<<<nb, 256, 0, stream>>>(mol, act, w_in, b_in, w_hid, b_hid, w_out, b_out,
                                   d_out, N, flag);
}

// Round 3
// 1397.806 us; speedup vs baseline: 2.1300x; 2.1300x over previous
//
#include <hip/hip_runtime.h>
#include <hip/hip_bf16.h>
#include <stdint.h>

// CriticGNN: two GraphConv branches + MLP head.
// R0: aggregate AFTER the 128->16 transform (segment_sum is linear).
// R1: runtime dtype detection (bf16 vs f32 device buffers).
// R2: replace f32-atomic scatter (800 MB write-through/pass, 85% of runtime)
//     with on-device CSR build (int atomics, counting sort by dst) + gather.

#define F_IN 128

__device__ __forceinline__ float bf2f(unsigned short u) {
    union { unsigned int i; float f; } v; v.i = ((unsigned int)u) << 16; return v.f;
}
__device__ __forceinline__ float bflo(unsigned int u) {
    union { unsigned int i; float f; } v; v.i = u << 16; return v.f;
}
__device__ __forceinline__ float bfhi(unsigned int u) {
    union { unsigned int i; float f; } v; v.i = u & 0xffff0000u; return v.f;
}
__device__ __forceinline__ unsigned short f2bf(float f) {
    union { float f; unsigned int i; } v; v.f = f;
    unsigned int u = v.i;
    unsigned int r = (u + 0x7fffu + ((u >> 16) & 1u)) >> 16;  // RNE
    return (unsigned short)r;
}
__device__ __forceinline__ float ldf(const void* p, int isf32, size_t i) {
    return isf32 ? ((const float*)p)[i] : bf2f(((const unsigned short*)p)[i]);
}

// Decide dtype: bf16 N(0,1) data has exponent ~[117,131]; f32 read as uint16
// pairs has ~45% random exponent fields.
__global__ __launch_bounds__(256) void k_detect(
    const unsigned short* __restrict__ x, int nProbe, int* __restrict__ flag)
{
    __shared__ int cnt;
    if (threadIdx.x == 0) cnt = 0;
    __syncthreads();
    int bad = 0;
    for (int i = threadIdx.x; i < nProbe; i += 256) {
        unsigned e = (x[i] >> 7) & 0xFFu;
        if (e >= 140u) bad++;
    }
    atomicAdd(&cnt, bad);
    __syncthreads();
    if (threadIdx.x == 0) *flag = (cnt > nProbe / 16) ? 1 : 0;
}

// ---------------- CSR build (counting sort by dst) ----------------

__global__ __launch_bounds__(256) void k_zero(int* __restrict__ p, int n) {
    int i = blockIdx.x * 256 + threadIdx.x;
    if (i < n) p[i] = 0;
}

__global__ __launch_bounds__(256) void k_hist(
    const int* __restrict__ edst, int* __restrict__ cnt, int nE)
{
    int e = blockIdx.x * 256 + threadIdx.x;
    if (e < nE) atomicAdd(&cnt[edst[e]], 1);
}

// per-1024-item block: exclusive prefix within block -> part, block sum -> bsum
__global__ __launch_bounds__(256) void k_scan_block(
    const int* __restrict__ cnt, int* __restrict__ part,
    int* __restrict__ bsum, int n)
{
    __shared__ int sh[256];
    int base = blockIdx.x * 1024;
    int i0 = base + threadIdx.x * 4;
    int v[4];
#pragma unroll
    for (int k = 0; k < 4; ++k) v[k] = (i0 + k < n) ? cnt[i0 + k] : 0;
    int s = v[0] + v[1] + v[2] + v[3];
    sh[threadIdx.x] = s;
    __syncthreads();
    for (int off = 1; off < 256; off <<= 1) {
        int t = (threadIdx.x >= off) ? sh[threadIdx.x - off] : 0;
        __syncthreads();
        sh[threadIdx.x] += t;
        __syncthreads();
    }
    int run = sh[threadIdx.x] - s;  // exclusive
#pragma unroll
    for (int k = 0; k < 4; ++k) {
        if (i0 + k < n) part[i0 + k] = run;
        run += v[k];
    }
    if (threadIdx.x == 255) bsum[blockIdx.x] = sh[255];
}

__global__ void k_scan_top(int* __restrict__ bsum, int nb) {
    if (threadIdx.x == 0 && blockIdx.x == 0) {
        int run = 0;
        for (int i = 0; i < nb; ++i) { int t = bsum[i]; bsum[i] = run; run += t; }
    }
}

__global__ __launch_bounds__(256) void k_scan_add(
    int* __restrict__ row, int* __restrict__ cursor,
    const int* __restrict__ bsum, int n, int nE)
{
    int base = blockIdx.x * 1024;
    int add = bsum[blockIdx.x];
    int i0 = base + threadIdx.x * 4;
#pragma unroll
    for (int k = 0; k < 4; ++k) {
        int i = i0 + k;
        if (i < n) { int r = row[i] + add; row[i] = r; cursor[i] = r; }
    }
    if (blockIdx.x == 0 && threadIdx.x == 0) row[n] = nE;
}

// srcs[pos] = src node id, grouped by dst
__global__ __launch_bounds__(256) void k_fill(
    const int* __restrict__ esrc, const int* __restrict__ edst,
    int* __restrict__ cursor, int* __restrict__ srcs, int nE)
{
    int e = blockIdx.x * 256 + threadIdx.x;
    if (e >= nE) return;
    int pos = atomicAdd(&cursor[edst[e]], 1);
    srcs[pos] = esrc[e];
}

// ---------------- dense compute ----------------

// acc1 = x @ w_self + bias ; n1 = x @ w_nbr   (x: [N,128], W: [128,16])
__global__ __launch_bounds__(256) void k_transform1(
    const void* __restrict__ x,
    const void* __restrict__ w_self,
    const void* __restrict__ w_nbr,
    const void* __restrict__ bias,
    float* __restrict__ acc1, float* __restrict__ n1, int n,
    const int* __restrict__ flag)
{
    const int isf32 = *flag;
    __shared__ float Wl[F_IN][32];  // cols 0..15 = w_self, 16..31 = w_nbr
    for (int idx = threadIdx.x; idx < F_IN * 32; idx += 256) {
        int k = idx >> 5, j = idx & 31;
        Wl[k][j] = (j < 16) ? ldf(w_self, isf32, k * 16 + j)
                            : ldf(w_nbr, isf32, k * 16 + (j - 16));
    }
    __syncthreads();
    int node = blockIdx.x * 256 + threadIdx.x;
    if (node >= n) return;
    float acc[32];
#pragma unroll
    for (int j = 0; j < 16; ++j) acc[j] = ldf(bias, isf32, j);
#pragma unroll
    for (int j = 16; j < 32; ++j) acc[j] = 0.f;

    if (isf32) {
        const float4* xrow = (const float4*)((const float*)x + (size_t)node * F_IN);
        for (int kk = 0; kk < 32; ++kk) {
            float4 q = xrow[kk];
            float xs[4] = {q.x, q.y, q.z, q.w};
            int kbase = kk * 4;
#pragma unroll
            for (int h = 0; h < 4; ++h) {
                float xv = xs[h];
                const float* wrow = &Wl[kbase + h][0];
#pragma unroll
                for (int j = 0; j < 32; ++j) acc[j] += xv * wrow[j];
            }
        }
    } else {
        const uint4* xrow = (const uint4*)((const unsigned short*)x + (size_t)node * F_IN);
        for (int kk = 0; kk < 16; ++kk) {
            uint4 q = xrow[kk];
            float xs[8] = {bflo(q.x), bfhi(q.x), bflo(q.y), bfhi(q.y),
                           bflo(q.z), bfhi(q.z), bflo(q.w), bfhi(q.w)};
            int kbase = kk * 8;
#pragma unroll
            for (int h = 0; h < 8; ++h) {
                float xv = xs[h];
                const float* wrow = &Wl[kbase + h][0];
#pragma unroll
                for (int j = 0; j < 32; ++j) acc[j] += xv * wrow[j];
            }
        }
    }
    float4* a4 = (float4*)(acc1 + (size_t)node * 16);
    float4* n4 = (float4*)(n1 + (size_t)node * 16);
#pragma unroll
    for (int t = 0; t < 4; ++t) {
        a4[t] = make_float4(acc[4 * t], acc[4 * t + 1], acc[4 * t + 2], acc[4 * t + 3]);
        n4[t] = make_float4(acc[16 + 4 * t], acc[17 + 4 * t], acc[18 + 4 * t], acc[19 + 4 * t]);
    }
}

// out[node,0:16] = (selfmode ? out[node] : 0) + sum_{s in srcs[row[node]..row[node+1])} val[s]
// 4 lanes per node, float4 per lane.
__global__ __launch_bounds__(256) void k_gather16(
    const int* __restrict__ row, const int* __restrict__ srcs,
    const float* __restrict__ val, float* __restrict__ out, int n, int selfmode)
{
    int t = blockIdx.x * 256 + threadIdx.x;
    int node = t >> 2;
    if (node >= n) return;
    int c = (t & 3) << 2;
    int rs = row[node], re = row[node + 1];
    float4 sum = make_float4(0.f, 0.f, 0.f, 0.f);
    if (selfmode) sum = *(const float4*)(out + ((size_t)node << 4) + c);
    for (int j = rs; j < re; ++j) {
        int s = srcs[j];
        const float4 v = *(const float4*)(val + ((size_t)s << 4) + c);
        sum.x += v.x; sum.y += v.y; sum.z += v.z; sum.w += v.w;
    }
    *(float4*)(out + ((size_t)node << 4) + c) = sum;
}

// p1 = relu(h1); mol[:,off:off+50) = p1 @ w2s + b2   (p1 saved to n1)
__global__ __launch_bounds__(256) void k_layer2a(
    const float* __restrict__ h1, float* __restrict__ p1, float* __restrict__ mol,
    const void* __restrict__ w2s, const void* __restrict__ b2, int colOff, int n,
    const int* __restrict__ flag)
{
    const int isf32 = *flag;
    __shared__ float Ws[16][50];
    __shared__ float Bs[50];
    for (int idx = threadIdx.x; idx < 800; idx += 256)
        Ws[idx / 50][idx % 50] = ldf(w2s, isf32, idx);
    if (threadIdx.x < 50) Bs[threadIdx.x] = ldf(b2, isf32, threadIdx.x);
    __syncthreads();
    int node = blockIdx.x * 256 + threadIdx.x;
    if (node >= n) return;
    float p[16];
    const float4* row = (const float4*)(h1 + (size_t)node * 16);
#pragma unroll
    for (int t = 0; t < 4; ++t) {
        float4 v = row[t];
        p[4 * t] = fmaxf(v.x, 0.f); p[4 * t + 1] = fmaxf(v.y, 0.f);
        p[4 * t + 2] = fmaxf(v.z, 0.f); p[4 * t + 3] = fmaxf(v.w, 0.f);
    }
    float4* pout = (float4*)(p1 + (size_t)node * 16);
#pragma unroll
    for (int t = 0; t < 4; ++t)
        pout[t] = make_float4(p[4 * t], p[4 * t + 1], p[4 * t + 2], p[4 * t + 3]);
    float acc[50];
#pragma unroll
    for (int j = 0; j < 50; ++j) acc[j] = Bs[j];
#pragma unroll
    for (int k = 0; k < 16; ++k) {
        float pv = p[k];
#pragma unroll
        for (int j = 0; j < 50; ++j) acc[j] += pv * Ws[k][j];
    }
    float* o = mol + (size_t)node * 100 + colOff;
#pragma unroll
    for (int j = 0; j < 50; ++j) o[j] = acc[j];
}

// mol[:, colOff..colOff+50) += agg2 @ w2n
__global__ __launch_bounds__(256) void k_layer2b(
    const float* __restrict__ agg2, float* __restrict__ mol,
    const void* __restrict__ w2n, int colOff, int n,
    const int* __restrict__ flag)
{
    const int isf32 = *flag;
    __shared__ float Ws[16][50];
    for (int idx = threadIdx.x; idx < 800; idx += 256)
        Ws[idx / 50][idx % 50] = ldf(w2n, isf32, idx);
    __syncthreads();
    int node = blockIdx.x * 256 + threadIdx.x;
    if (node >= n) return;
    float g[16];
    const float4* grow = (const float4*)(agg2 + (size_t)node * 16);
#pragma unroll
    for (int t = 0; t < 4; ++t) {
        float4 v = grow[t];
        g[4 * t] = v.x; g[4 * t + 1] = v.y; g[4 * t + 2] = v.z; g[4 * t + 3] = v.w;
    }
    float* o = mol + (size_t)node * 100 + colOff;
    float acc[50];
#pragma unroll
    for (int j = 0; j < 50; ++j) acc[j] = o[j];
#pragma unroll
    for (int k = 0; k < 16; ++k) {
        float gv = g[k];
#pragma unroll
        for (int j = 0; j < 50; ++j) acc[j] += gv * Ws[k][j];
    }
#pragma unroll
    for (int j = 0; j < 50; ++j) o[j] = acc[j];
}

// head: fp = relu(mol@w_in+b_in); h = relu([fp,action]@w_hid+b_hid); out = h@w_out+b_out
__global__ __launch_bounds__(256) void k_head(
    const float* __restrict__ mol, const void* __restrict__ action,
    const void* __restrict__ w_in, const void* __restrict__ b_in,
    const void* __restrict__ w_hid, const void* __restrict__ b_hid,
    const void* __restrict__ w_out, const void* __restrict__ b_out,
    void* __restrict__ out, int n, const int* __restrict__ flag)
{
    const int isf32 = *flag;
    __shared__ float Win[100 * 60];
    __shared__ float Whid[70 * 10];
    __shared__ float Bin[60], Bhid[10], Wout[10];
    __shared__ float Bout;
    for (int idx = threadIdx.x; idx < 6000; idx += 256) Win[idx] = ldf(w_in, isf32, idx);
    for (int idx = threadIdx.x; idx < 700; idx += 256) Whid[idx] = ldf(w_hid, isf32, idx);
    if (threadIdx.x < 60) Bin[threadIdx.x] = ldf(b_in, isf32, threadIdx.x);
    if (threadIdx.x < 10) {
        Bhid[threadIdx.x] = ldf(b_hid, isf32, threadIdx.x);
        Wout[threadIdx.x] = ldf(w_out, isf32, threadIdx.x);
    }
    if (threadIdx.x == 0) Bout = ldf(b_out, isf32, 0);
    __syncthreads();
    int node = blockIdx.x * 256 + threadIdx.x;
    if (node >= n) return;
    float fp[60];
#pragma unroll
    for (int j = 0; j < 60; ++j) fp[j] = Bin[j];
    const float* mrow = mol + (size_t)node * 100;
    for (int k = 0; k < 100; ++k) {
        float m = mrow[k];
        const float* w = &Win[k * 60];
#pragma unroll
        for (int j = 0; j < 60; ++j) fp[j] += m * w[j];
    }
    float h[10];
#pragma unroll
    for (int j = 0; j < 10; ++j) h[j] = Bhid[j];
#pragma unroll
    for (int k = 0; k < 60; ++k) {
        float v = fmaxf(fp[k], 0.f);
        const float* w = &Whid[k * 10];
#pragma unroll
        for (int j = 0; j < 10; ++j) h[j] += v * w[j];
    }
#pragma unroll
    for (int k = 0; k < 10; ++k) {
        float v = ldf(action, isf32, (size_t)node * 10 + k);
        const float* w = &Whid[(60 + k) * 10];
#pragma unroll
        for (int j = 0; j < 10; ++j) h[j] += v * w[j];
    }
    float o = Bout;
#pragma unroll
    for (int j = 0; j < 10; ++j) o += fmaxf(h[j], 0.f) * Wout[j];
    if (isf32) ((float*)out)[node] = o;
    else       ((unsigned short*)out)[node] = f2bf(o);
}

extern "C" void kernel_launch(void* const* d_in, const int* in_sizes, int n_in,
                              void* d_out, int out_size, void* d_ws, size_t ws_size,
                              hipStream_t stream)
{
    const void* px   = d_in[0];
    const int*  pe   = (const int*)d_in[1];
    const void* lx   = d_in[2];
    const int*  le   = (const int*)d_in[3];
    const void* act  = d_in[4];
    const void* wp1s = d_in[5];
    const void* wp1n = d_in[6];
    const void* bp1  = d_in[7];
    const void* wp2s = d_in[8];
    const void* wp2n = d_in[9];
    const void* bp2  = d_in[10];
    const void* wl1s = d_in[11];
    const void* wl1n = d_in[12];
    const void* bl1  = d_in[13];
    const void* wl2s = d_in[14];
    const void* wl2n = d_in[15];
    const void* bl2  = d_in[16];
    const void* w_in  = d_in[17];
    const void* b_in  = d_in[18];
    const void* w_hid = d_in[19];
    const void* b_hid = d_in[20];
    const void* w_out = d_in[21];
    const void* b_out = d_in[22];

    const int N = in_sizes[0] / F_IN;
    const int E = in_sizes[1] / 2;

    // workspace layout (f32/int):
    // flag(256B) | acc1[16N] | n1[16N] | mol[100N] | row[N+1] | cursor[N] | srcs[E] | bsum[256]
    int* flag   = (int*)d_ws;
    float* acc1 = (float*)((char*)d_ws + 256);
    float* n1   = acc1 + (size_t)N * 16;
    float* mol  = n1 + (size_t)N * 16;
    int* row    = (int*)(mol + (size_t)N * 100);
    int* cursor = row + (N + 1);
    int* srcs   = cursor + N;
    int* bsum   = srcs + E;

    const int nb  = (N + 255) / 256;        // node-parallel blocks
    const int gb  = (N * 4 + 255) / 256;    // gather blocks (4 lanes/node)
    const int eb  = (E + 255) / 256;        // edge-parallel blocks
    const int sb2 = (N + 1023) / 1024;      // scan blocks

    k_detect<<<1, 256, 0, stream>>>((const unsigned short*)px, 4096, flag);

#define BUILD_CSR(EDGES)                                                         \
    k_zero<<<nb, 256, 0, stream>>>(cursor, N);                                   \
    k_hist<<<eb, 256, 0, stream>>>((EDGES) + E, cursor, E);                      \
    k_scan_block<<<sb2, 256, 0, stream>>>(cursor, row, bsum, N);                 \
    k_scan_top<<<1, 64, 0, stream>>>(bsum, sb2);                                 \
    k_scan_add<<<sb2, 256, 0, stream>>>(row, cursor, bsum, N, E);                \
    k_fill<<<eb, 256, 0, stream>>>((EDGES), (EDGES) + E, cursor, srcs, E)

    // ---- protein branch -> mol[:, 0:50]
    BUILD_CSR(pe);
    k_transform1<<<nb, 256, 0, stream>>>(px, wp1s, wp1n, bp1, acc1, n1, N, flag);
    k_gather16<<<gb, 256, 0, stream>>>(row, srcs, n1, acc1, N, 1);   // h1 in acc1
    k_layer2a<<<nb, 256, 0, stream>>>(acc1, n1, mol, wp2s, bp2, 0, N, flag);  // p1 -> n1
    k_gather16<<<gb, 256, 0, stream>>>(row, srcs, n1, acc1, N, 0);   // agg2 in acc1
    k_layer2b<<<nb, 256, 0, stream>>>(acc1, mol, wp2n, 0, N, flag);

    // ---- ligand branch -> mol[:, 50:100]
    BUILD_CSR(le);
    k_transform1<<<nb, 256, 0, stream>>>(lx, wl1s, wl1n, bl1, acc1, n1, N, flag);
    k_gather16<<<gb, 256, 0, stream>>>(row, srcs, n1, acc1, N, 1);
    k_layer2a<<<nb, 256, 0, stream>>>(acc1, n1, mol, wl2s, bl2, 50, N, flag);
    k_gather16<<<gb, 256, 0, stream>>>(row, srcs, n1, acc1, N, 0);
    k_layer2b<<<nb, 256, 0, stream>>>(acc1, mol, wl2n, 50, N, flag);

    // ---- head
    k_head<<<nb, 256, 0, stream>>>(mol, act, w_in, b_in, w_hid, b_hid, w_out, b_out,
                                   d_out, N, flag);
#undef BUILD_CSR
}

// Round 4
// 866.765 us; speedup vs baseline: 3.4351x; 1.6127x over previous
//
#include <hip/hip_runtime.h>
#include <hip/hip_bf16.h>
#include <stdint.h>

// CriticGNN: two GraphConv branches + MLP head.
// R0: aggregate AFTER the 128->16 transform (segment_sum is linear).
// R1: runtime dtype detection (bf16 vs f32 device buffers).
// R2: CSR (counting sort by dst) + gather instead of f32 atomics.
// R3: k_fill had 195 MB WRITE_SIZE (16x write amplification from random 4B
//     scatter) + 3.2M random global atomics in hist/fill. Replace with
//     two-level bucketed counting sort: LDS histograms, burst writes.

#define F_IN 128
#define NBMAX 512   // max coarse buckets (N <= 131072)

__device__ __forceinline__ float bf2f(unsigned short u) {
    union { unsigned int i; float f; } v; v.i = ((unsigned int)u) << 16; return v.f;
}
__device__ __forceinline__ float bflo(unsigned int u) {
    union { unsigned int i; float f; } v; v.i = u << 16; return v.f;
}
__device__ __forceinline__ float bfhi(unsigned int u) {
    union { unsigned int i; float f; } v; v.i = u & 0xffff0000u; return v.f;
}
__device__ __forceinline__ unsigned short f2bf(float f) {
    union { float f; unsigned int i; } v; v.f = f;
    unsigned int u = v.i;
    unsigned int r = (u + 0x7fffu + ((u >> 16) & 1u)) >> 16;  // RNE
    return (unsigned short)r;
}
__device__ __forceinline__ float ldf(const void* p, int isf32, size_t i) {
    return isf32 ? ((const float*)p)[i] : bf2f(((const unsigned short*)p)[i]);
}

__global__ __launch_bounds__(256) void k_detect(
    const unsigned short* __restrict__ x, int nProbe, int* __restrict__ flag)
{
    __shared__ int cnt;
    if (threadIdx.x == 0) cnt = 0;
    __syncthreads();
    int bad = 0;
    for (int i = threadIdx.x; i < nProbe; i += 256) {
        unsigned e = (x[i] >> 7) & 0xFFu;
        if (e >= 140u) bad++;
    }
    atomicAdd(&cnt, bad);
    __syncthreads();
    if (threadIdx.x == 0) *flag = (cnt > nProbe / 16) ? 1 : 0;
}

// ---------------- bucketed CSR build ----------------

__global__ __launch_bounds__(256) void k_zero(int* __restrict__ p, int n) {
    int i = blockIdx.x * 256 + threadIdx.x;
    if (i < n) p[i] = 0;
}

// coarse histogram: bucket = dst >> 8
__global__ __launch_bounds__(256) void k_bucket_hist(
    const int* __restrict__ edst, int* __restrict__ cnt, int nE)
{
    __shared__ int h[NBMAX];
    for (int i = threadIdx.x; i < NBMAX; i += 256) h[i] = 0;
    __syncthreads();
    int stride = gridDim.x * 256;
    for (int e = blockIdx.x * 256 + threadIdx.x; e < nE; e += stride)
        atomicAdd(&h[edst[e] >> 8], 1);
    __syncthreads();
    for (int i = threadIdx.x; i < NBMAX; i += 256)
        if (h[i]) atomicAdd(&cnt[i], h[i]);
}

// single block: exclusive scan of nb bucket counts -> base[0..nb], cursor=base
__global__ __launch_bounds__(512) void k_bucket_scan(
    const int* __restrict__ cnt, int* __restrict__ base,
    int* __restrict__ cursor, int nb)
{
    __shared__ int sh[512];
    int t = threadIdx.x;
    int v = (t < nb) ? cnt[t] : 0;
    sh[t] = v;
    __syncthreads();
    for (int off = 1; off < 512; off <<= 1) {
        int x = (t >= off) ? sh[t - off] : 0;
        __syncthreads();
        sh[t] += x;
        __syncthreads();
    }
    int excl = sh[t] - v;
    if (t < nb) { base[t] = excl; cursor[t] = excl; }
    if (t == nb - 1) base[nb] = excl + v;
}

// bin edges into bucket-contiguous pairs array (burst writes per bucket)
#define BIN_CH 16
__global__ __launch_bounds__(256) void k_bucket_bin(
    const int* __restrict__ esrc, const int* __restrict__ edst,
    int* __restrict__ cursor, int2* __restrict__ pairs, int nE)
{
    __shared__ int h[NBMAX];
    for (int i = threadIdx.x; i < NBMAX; i += 256) h[i] = 0;
    __syncthreads();
    int e0 = blockIdx.x * (256 * BIN_CH);
    int s[BIN_CH], d[BIN_CH];
#pragma unroll
    for (int k = 0; k < BIN_CH; ++k) {
        int e = e0 + k * 256 + threadIdx.x;
        if (e < nE) {
            s[k] = esrc[e]; d[k] = edst[e];
            atomicAdd(&h[d[k] >> 8], 1);
        } else d[k] = -1;
    }
    __syncthreads();
    for (int b = threadIdx.x; b < NBMAX; b += 256) {
        int c = h[b];
        if (c) h[b] = atomicAdd(&cursor[b], c);   // h[b] := global write cursor
    }
    __syncthreads();
#pragma unroll
    for (int k = 0; k < BIN_CH; ++k) {
        if (d[k] >= 0) {
            int pos = atomicAdd(&h[d[k] >> 8], 1);
            pairs[pos] = make_int2(s[k], d[k]);
        }
    }
}

// one block per bucket: fine counting sort of 256 nodes, write row + srcs
__global__ __launch_bounds__(256) void k_bucket_fine(
    const int2* __restrict__ pairs, const int* __restrict__ base,
    int* __restrict__ row, int* __restrict__ srcs, int n, int nE, int nb)
{
    __shared__ int cnt[256], cur[256];
    int b = blockIdx.x;
    int t = threadIdx.x;
    int s0 = base[b], s1 = base[b + 1];
    cnt[t] = 0;
    __syncthreads();
    for (int i = s0 + t; i < s1; i += 256)
        atomicAdd(&cnt[pairs[i].y & 255], 1);
    __syncthreads();
    int c = cnt[t];
    cur[t] = c;
    __syncthreads();
    for (int off = 1; off < 256; off <<= 1) {
        int x = (t >= off) ? cur[t - off] : 0;
        __syncthreads();
        cur[t] += x;
        __syncthreads();
    }
    int excl = cur[t] - c;
    __syncthreads();
    cur[t] = s0 + excl;
    int node = (b << 8) + t;
    if (node < n) row[node] = s0 + excl;
    if (b == nb - 1 && t == 0) row[n] = nE;
    __syncthreads();
    for (int i = s0 + t; i < s1; i += 256) {
        int2 p = pairs[i];
        int slot = atomicAdd(&cur[p.y & 255], 1);
        srcs[slot] = p.x;
    }
}

// ---------------- dense compute ----------------

// acc1 = x @ w_self + bias ; n1 = x @ w_nbr   (x: [N,128], W: [128,16])
__global__ __launch_bounds__(256) void k_transform1(
    const void* __restrict__ x,
    const void* __restrict__ w_self,
    const void* __restrict__ w_nbr,
    const void* __restrict__ bias,
    float* __restrict__ acc1, float* __restrict__ n1, int n,
    const int* __restrict__ flag)
{
    const int isf32 = *flag;
    __shared__ float Wl[F_IN][32];  // cols 0..15 = w_self, 16..31 = w_nbr
    for (int idx = threadIdx.x; idx < F_IN * 32; idx += 256) {
        int k = idx >> 5, j = idx & 31;
        Wl[k][j] = (j < 16) ? ldf(w_self, isf32, k * 16 + j)
                            : ldf(w_nbr, isf32, k * 16 + (j - 16));
    }
    __syncthreads();
    int node = blockIdx.x * 256 + threadIdx.x;
    if (node >= n) return;
    float acc[32];
#pragma unroll
    for (int j = 0; j < 16; ++j) acc[j] = ldf(bias, isf32, j);
#pragma unroll
    for (int j = 16; j < 32; ++j) acc[j] = 0.f;

    if (isf32) {
        const float4* xrow = (const float4*)((const float*)x + (size_t)node * F_IN);
        for (int kk = 0; kk < 32; ++kk) {
            float4 q = xrow[kk];
            float xs[4] = {q.x, q.y, q.z, q.w};
            int kbase = kk * 4;
#pragma unroll
            for (int h = 0; h < 4; ++h) {
                float xv = xs[h];
                const float* wrow = &Wl[kbase + h][0];
#pragma unroll
                for (int j = 0; j < 32; ++j) acc[j] += xv * wrow[j];
            }
        }
    } else {
        const uint4* xrow = (const uint4*)((const unsigned short*)x + (size_t)node * F_IN);
        for (int kk = 0; kk < 16; ++kk) {
            uint4 q = xrow[kk];
            float xs[8] = {bflo(q.x), bfhi(q.x), bflo(q.y), bfhi(q.y),
                           bflo(q.z), bfhi(q.z), bflo(q.w), bfhi(q.w)};
            int kbase = kk * 8;
#pragma unroll
            for (int h = 0; h < 8; ++h) {
                float xv = xs[h];
                const float* wrow = &Wl[kbase + h][0];
#pragma unroll
                for (int j = 0; j < 32; ++j) acc[j] += xv * wrow[j];
            }
        }
    }
    float4* a4 = (float4*)(acc1 + (size_t)node * 16);
    float4* n4 = (float4*)(n1 + (size_t)node * 16);
#pragma unroll
    for (int t = 0; t < 4; ++t) {
        a4[t] = make_float4(acc[4 * t], acc[4 * t + 1], acc[4 * t + 2], acc[4 * t + 3]);
        n4[t] = make_float4(acc[16 + 4 * t], acc[17 + 4 * t], acc[18 + 4 * t], acc[19 + 4 * t]);
    }
}

// out[node,0:16] = (selfmode ? out[node] : 0) + sum_{neighbors} val[s]
__global__ __launch_bounds__(256) void k_gather16(
    const int* __restrict__ row, const int* __restrict__ srcs,
    const float* __restrict__ val, float* __restrict__ out, int n, int selfmode)
{
    int t = blockIdx.x * 256 + threadIdx.x;
    int node = t >> 2;
    if (node >= n) return;
    int c = (t & 3) << 2;
    int rs = row[node], re = row[node + 1];
    float4 sum = make_float4(0.f, 0.f, 0.f, 0.f);
    if (selfmode) sum = *(const float4*)(out + ((size_t)node << 4) + c);
    for (int j = rs; j < re; ++j) {
        int s = srcs[j];
        const float4 v = *(const float4*)(val + ((size_t)s << 4) + c);
        sum.x += v.x; sum.y += v.y; sum.z += v.z; sum.w += v.w;
    }
    *(float4*)(out + ((size_t)node << 4) + c) = sum;
}

// p1 = relu(h1); mol[:,off:off+50) = p1 @ w2s + b2   (p1 saved to n1)
__global__ __launch_bounds__(256) void k_layer2a(
    const float* __restrict__ h1, float* __restrict__ p1, float* __restrict__ mol,
    const void* __restrict__ w2s, const void* __restrict__ b2, int colOff, int n,
    const int* __restrict__ flag)
{
    const int isf32 = *flag;
    __shared__ float Ws[16][50];
    __shared__ float Bs[50];
    for (int idx = threadIdx.x; idx < 800; idx += 256)
        Ws[idx / 50][idx % 50] = ldf(w2s, isf32, idx);
    if (threadIdx.x < 50) Bs[threadIdx.x] = ldf(b2, isf32, threadIdx.x);
    __syncthreads();
    int node = blockIdx.x * 256 + threadIdx.x;
    if (node >= n) return;
    float p[16];
    const float4* row = (const float4*)(h1 + (size_t)node * 16);
#pragma unroll
    for (int t = 0; t < 4; ++t) {
        float4 v = row[t];
        p[4 * t] = fmaxf(v.x, 0.f); p[4 * t + 1] = fmaxf(v.y, 0.f);
        p[4 * t + 2] = fmaxf(v.z, 0.f); p[4 * t + 3] = fmaxf(v.w, 0.f);
    }
    float4* pout = (float4*)(p1 + (size_t)node * 16);
#pragma unroll
    for (int t = 0; t < 4; ++t)
        pout[t] = make_float4(p[4 * t], p[4 * t + 1], p[4 * t + 2], p[4 * t + 3]);
    float acc[50];
#pragma unroll
    for (int j = 0; j < 50; ++j) acc[j] = Bs[j];
#pragma unroll
    for (int k = 0; k < 16; ++k) {
        float pv = p[k];
#pragma unroll
        for (int j = 0; j < 50; ++j) acc[j] += pv * Ws[k][j];
    }
    float* o = mol + (size_t)node * 100 + colOff;
#pragma unroll
    for (int j = 0; j < 50; ++j) o[j] = acc[j];
}

// mol[:, colOff..colOff+50) += agg2 @ w2n
__global__ __launch_bounds__(256) void k_layer2b(
    const float* __restrict__ agg2, float* __restrict__ mol,
    const void* __restrict__ w2n, int colOff, int n,
    const int* __restrict__ flag)
{
    const int isf32 = *flag;
    __shared__ float Ws[16][50];
    for (int idx = threadIdx.x; idx < 800; idx += 256)
        Ws[idx / 50][idx % 50] = ldf(w2n, isf32, idx);
    __syncthreads();
    int node = blockIdx.x * 256 + threadIdx.x;
    if (node >= n) return;
    float g[16];
    const float4* grow = (const float4*)(agg2 + (size_t)node * 16);
#pragma unroll
    for (int t = 0; t < 4; ++t) {
        float4 v = grow[t];
        g[4 * t] = v.x; g[4 * t + 1] = v.y; g[4 * t + 2] = v.z; g[4 * t + 3] = v.w;
    }
    float* o = mol + (size_t)node * 100 + colOff;
    float acc[50];
#pragma unroll
    for (int j = 0; j < 50; ++j) acc[j] = o[j];
#pragma unroll
    for (int k = 0; k < 16; ++k) {
        float gv = g[k];
#pragma unroll
        for (int j = 0; j < 50; ++j) acc[j] += gv * Ws[k][j];
    }
#pragma unroll
    for (int j = 0; j < 50; ++j) o[j] = acc[j];
}

// head: fp = relu(mol@w_in+b_in); h = relu([fp,action]@w_hid+b_hid); out = h@w_out+b_out
__global__ __launch_bounds__(256) void k_head(
    const float* __restrict__ mol, const void* __restrict__ action,
    const void* __restrict__ w_in, const void* __restrict__ b_in,
    const void* __restrict__ w_hid, const void* __restrict__ b_hid,
    const void* __restrict__ w_out, const void* __restrict__ b_out,
    void* __restrict__ out, int n, const int* __restrict__ flag)
{
    const int isf32 = *flag;
    __shared__ float Win[100 * 60];
    __shared__ float Whid[70 * 10];
    __shared__ float Bin[60], Bhid[10], Wout[10];
    __shared__ float Bout;
    for (int idx = threadIdx.x; idx < 6000; idx += 256) Win[idx] = ldf(w_in, isf32, idx);
    for (int idx = threadIdx.x; idx < 700; idx += 256) Whid[idx] = ldf(w_hid, isf32, idx);
    if (threadIdx.x < 60) Bin[threadIdx.x] = ldf(b_in, isf32, threadIdx.x);
    if (threadIdx.x < 10) {
        Bhid[threadIdx.x] = ldf(b_hid, isf32, threadIdx.x);
        Wout[threadIdx.x] = ldf(w_out, isf32, threadIdx.x);
    }
    if (threadIdx.x == 0) Bout = ldf(b_out, isf32, 0);
    __syncthreads();
    int node = blockIdx.x * 256 + threadIdx.x;
    if (node >= n) return;
    float fp[60];
#pragma unroll
    for (int j = 0; j < 60; ++j) fp[j] = Bin[j];
    const float* mrow = mol + (size_t)node * 100;
    for (int k = 0; k < 100; ++k) {
        float m = mrow[k];
        const float* w = &Win[k * 60];
#pragma unroll
        for (int j = 0; j < 60; ++j) fp[j] += m * w[j];
    }
    float h[10];
#pragma unroll
    for (int j = 0; j < 10; ++j) h[j] = Bhid[j];
#pragma unroll
    for (int k = 0; k < 60; ++k) {
        float v = fmaxf(fp[k], 0.f);
        const float* w = &Whid[k * 10];
#pragma unroll
        for (int j = 0; j < 10; ++j) h[j] += v * w[j];
    }
#pragma unroll
    for (int k = 0; k < 10; ++k) {
        float v = ldf(action, isf32, (size_t)node * 10 + k);
        const float* w = &Whid[(60 + k) * 10];
#pragma unroll
        for (int j = 0; j < 10; ++j) h[j] += v * w[j];
    }
    float o = Bout;
#pragma unroll
    for (int j = 0; j < 10; ++j) o += fmaxf(h[j], 0.f) * Wout[j];
    if (isf32) ((float*)out)[node] = o;
    else       ((unsigned short*)out)[node] = f2bf(o);
}

extern "C" void kernel_launch(void* const* d_in, const int* in_sizes, int n_in,
                              void* d_out, int out_size, void* d_ws, size_t ws_size,
                              hipStream_t stream)
{
    const void* px   = d_in[0];
    const int*  pe   = (const int*)d_in[1];
    const void* lx   = d_in[2];
    const int*  le   = (const int*)d_in[3];
    const void* act  = d_in[4];
    const void* wp1s = d_in[5];
    const void* wp1n = d_in[6];
    const void* bp1  = d_in[7];
    const void* wp2s = d_in[8];
    const void* wp2n = d_in[9];
    const void* bp2  = d_in[10];
    const void* wl1s = d_in[11];
    const void* wl1n = d_in[12];
    const void* bl1  = d_in[13];
    const void* wl2s = d_in[14];
    const void* wl2n = d_in[15];
    const void* bl2  = d_in[16];
    const void* w_in  = d_in[17];
    const void* b_in  = d_in[18];
    const void* w_hid = d_in[19];
    const void* b_hid = d_in[20];
    const void* w_out = d_in[21];
    const void* b_out = d_in[22];

    const int N = in_sizes[0] / F_IN;
    const int E = in_sizes[1] / 2;
    const int NB = (N + 255) >> 8;      // coarse buckets (256 nodes each)

    // ws layout (all 4B elems; offsets stay 16B-aligned):
    // flag(64) | cnt(1024) | base(1024) | cursorB(1024) | rowP(N+64) | srcsP(E)
    // | rowL(N+64) | srcsL(E) | acc1(16N) | n1(16N) | mol(100N)  [pairs overlaps mol]
    int* flag    = (int*)d_ws;
    int* cnt     = flag + 64;
    int* base    = cnt + 1024;
    int* cursorB = base + 1024;
    int* rowP    = cursorB + 1024;
    int* srcsP   = rowP + (N + 64);
    int* rowL    = srcsP + E;
    int* srcsL   = rowL + (N + 64);
    float* acc1  = (float*)(srcsL + E);
    float* n1    = acc1 + (size_t)N * 16;
    float* mol   = n1 + (size_t)N * 16;
    int2* pairs  = (int2*)mol;          // scratch; dead before mol is written

    const int nb  = (N + 255) / 256;         // node-parallel blocks
    const int gb  = (N * 4 + 255) / 256;     // gather blocks (4 lanes/node)
    const int bb  = (E + 4095) / 4096;       // bin blocks

    k_detect<<<1, 256, 0, stream>>>((const unsigned short*)px, 4096, flag);

#define BUILD_CSR(EDGES, ROW, SRCS)                                              \
    k_zero<<<3, 256, 0, stream>>>(cnt, NB + 1);                                  \
    k_bucket_hist<<<512, 256, 0, stream>>>((EDGES) + E, cnt, E);                 \
    k_bucket_scan<<<1, 512, 0, stream>>>(cnt, base, cursorB, NB);                \
    k_bucket_bin<<<bb, 256, 0, stream>>>((EDGES), (EDGES) + E, cursorB, pairs, E); \
    k_bucket_fine<<<NB, 256, 0, stream>>>(pairs, base, (ROW), (SRCS), N, E, NB)

    // ---- build both CSRs first (pairs scratch overlaps mol) ----
    BUILD_CSR(pe, rowP, srcsP);
    BUILD_CSR(le, rowL, srcsL);

    // ---- protein branch -> mol[:, 0:50]
    k_transform1<<<nb, 256, 0, stream>>>(px, wp1s, wp1n, bp1, acc1, n1, N, flag);
    k_gather16<<<gb, 256, 0, stream>>>(rowP, srcsP, n1, acc1, N, 1);   // h1 in acc1
    k_layer2a<<<nb, 256, 0, stream>>>(acc1, n1, mol, wp2s, bp2, 0, N, flag);  // p1 -> n1
    k_gather16<<<gb, 256, 0, stream>>>(rowP, srcsP, n1, acc1, N, 0);   // agg2 in acc1
    k_layer2b<<<nb, 256, 0, stream>>>(acc1, mol, wp2n, 0, N, flag);

    // ---- ligand branch -> mol[:, 50:100]
    k_transform1<<<nb, 256, 0, stream>>>(lx, wl1s, wl1n, bl1, acc1, n1, N, flag);
    k_gather16<<<gb, 256, 0, stream>>>(rowL, srcsL, n1, acc1, N, 1);
    k_layer2a<<<nb, 256, 0, stream>>>(acc1, n1, mol, wl2s, bl2, 50, N, flag);
    k_gather16<<<gb, 256, 0, stream>>>(rowL, srcsL, n1, acc1, N, 0);
    k_layer2b<<<nb, 256, 0, stream>>>(acc1, mol, wl2n, 50, N, flag);

    // ---- head
    k_head<<<nb, 256, 0, stream>>>(mol, act, w_in, b_in, w_hid, b_hid, w_out, b_out,
                                   d_out, N, flag);
#undef BUILD_CSR
}

// Round 5
// 792.228 us; speedup vs baseline: 3.7583x; 1.0941x over previous
//
#include <hip/hip_runtime.h>
#include <hip/hip_bf16.h>
#include <stdint.h>

// CriticGNN: two GraphConv branches + MLP head.
// R0: aggregate AFTER the 128->16 transform (segment_sum is linear).
// R1: runtime dtype detection (bf16 vs f32 device buffers).
// R2: CSR (counting sort by dst) + gather instead of f32 atomics.
// R3: two-level bucketed counting sort (LDS histograms, burst writes).
// R4: k_head spilled (VGPR=256, WRITE 103MB of scratch) -> split fp[60] into
//     2x30 passes. Gather: 4x unroll for load ILP. Fuse both graphs/branches
//     into gridDim.y=2 dispatches; pack bin pairs to 4B.

#define F_IN 128
#define NBMAX 512   // max coarse buckets (N <= 131072)

__device__ __forceinline__ float bf2f(unsigned short u) {
    union { unsigned int i; float f; } v; v.i = ((unsigned int)u) << 16; return v.f;
}
__device__ __forceinline__ float bflo(unsigned int u) {
    union { unsigned int i; float f; } v; v.i = u << 16; return v.f;
}
__device__ __forceinline__ float bfhi(unsigned int u) {
    union { unsigned int i; float f; } v; v.i = u & 0xffff0000u; return v.f;
}
__device__ __forceinline__ unsigned short f2bf(float f) {
    union { float f; unsigned int i; } v; v.f = f;
    unsigned int u = v.i;
    unsigned int r = (u + 0x7fffu + ((u >> 16) & 1u)) >> 16;  // RNE
    return (unsigned short)r;
}
__device__ __forceinline__ float ldf(const void* p, int isf32, size_t i) {
    return isf32 ? ((const float*)p)[i] : bf2f(((const unsigned short*)p)[i]);
}

__global__ __launch_bounds__(256) void k_detect(
    const unsigned short* __restrict__ x, int nProbe, int* __restrict__ flag)
{
    __shared__ int cnt;
    if (threadIdx.x == 0) cnt = 0;
    __syncthreads();
    int bad = 0;
    for (int i = threadIdx.x; i < nProbe; i += 256) {
        unsigned e = (x[i] >> 7) & 0xFFu;
        if (e >= 140u) bad++;
    }
    atomicAdd(&cnt, bad);
    __syncthreads();
    if (threadIdx.x == 0) *flag = (cnt > nProbe / 16) ? 1 : 0;
}

// ---------------- bucketed CSR build (both graphs via blockIdx.y) ----------------

__global__ __launch_bounds__(256) void k_zero(int* __restrict__ p, int n) {
    int i = blockIdx.x * 256 + threadIdx.x;
    if (i < n) p[i] = 0;
}

__global__ __launch_bounds__(256) void k_bucket_hist(
    const int* __restrict__ ed0, const int* __restrict__ ed1,
    int* __restrict__ cnt, int nE)
{
    const int* ed = blockIdx.y ? ed1 : ed0;
    int* c = cnt + blockIdx.y * NBMAX;
    __shared__ int h[NBMAX];
    for (int i = threadIdx.x; i < NBMAX; i += 256) h[i] = 0;
    __syncthreads();
    int stride = gridDim.x * 256;
    for (int e = blockIdx.x * 256 + threadIdx.x; e < nE; e += stride)
        atomicAdd(&h[ed[e] >> 8], 1);
    __syncthreads();
    for (int i = threadIdx.x; i < NBMAX; i += 256)
        if (h[i]) atomicAdd(&c[i], h[i]);
}

// one block per graph: exclusive scan of nb bucket counts
__global__ __launch_bounds__(512) void k_bucket_scan(
    const int* __restrict__ cnt, int* __restrict__ base,
    int* __restrict__ cursor, int nb)
{
    const int* c = cnt + blockIdx.x * NBMAX;
    int* ba = base + blockIdx.x * 528;
    int* cu = cursor + blockIdx.x * NBMAX;
    __shared__ int sh[512];
    int t = threadIdx.x;
    int v = (t < nb) ? c[t] : 0;
    sh[t] = v;
    __syncthreads();
    for (int off = 1; off < 512; off <<= 1) {
        int x = (t >= off) ? sh[t - off] : 0;
        __syncthreads();
        sh[t] += x;
        __syncthreads();
    }
    int excl = sh[t] - v;
    if (t < nb) { ba[t] = excl; cu[t] = excl; }
    if (t == nb - 1) ba[nb] = excl + v;
}

// bin edges into bucket-contiguous packed array: (dstLow8 << 24) | src
#define BIN_CH 16
__global__ __launch_bounds__(256) void k_bucket_bin(
    const int* __restrict__ es0, const int* __restrict__ ed0,
    const int* __restrict__ es1, const int* __restrict__ ed1,
    int* __restrict__ cursor, unsigned* __restrict__ pairs, int nE)
{
    const int* es = blockIdx.y ? es1 : es0;
    const int* ed = blockIdx.y ? ed1 : ed0;
    int* cur = cursor + blockIdx.y * NBMAX;
    unsigned* pr = pairs + (size_t)blockIdx.y * nE;
    __shared__ int h[NBMAX];
    for (int i = threadIdx.x; i < NBMAX; i += 256) h[i] = 0;
    __syncthreads();
    int e0 = blockIdx.x * (256 * BIN_CH);
    int s[BIN_CH], d[BIN_CH];
#pragma unroll
    for (int k = 0; k < BIN_CH; ++k) {
        int e = e0 + k * 256 + threadIdx.x;
        if (e < nE) {
            s[k] = es[e]; d[k] = ed[e];
            atomicAdd(&h[d[k] >> 8], 1);
        } else d[k] = -1;
    }
    __syncthreads();
    for (int b = threadIdx.x; b < NBMAX; b += 256) {
        int c = h[b];
        if (c) h[b] = atomicAdd(&cur[b], c);   // h[b] := global write cursor
    }
    __syncthreads();
#pragma unroll
    for (int k = 0; k < BIN_CH; ++k) {
        if (d[k] >= 0) {
            int pos = atomicAdd(&h[d[k] >> 8], 1);
            pr[pos] = ((unsigned)(d[k] & 255) << 24) | (unsigned)s[k];
        }
    }
}

// one block per bucket: fine counting sort of 256 nodes, write row + srcs
__global__ __launch_bounds__(256) void k_bucket_fine(
    const unsigned* __restrict__ pairs, const int* __restrict__ base,
    int* __restrict__ row0, int* __restrict__ srcs0,
    int* __restrict__ row1, int* __restrict__ srcs1,
    int n, int nE, int nb)
{
    const unsigned* pr = pairs + (size_t)blockIdx.y * nE;
    const int* ba = base + blockIdx.y * 528;
    int* row = blockIdx.y ? row1 : row0;
    int* srcs = blockIdx.y ? srcs1 : srcs0;
    __shared__ int cnt[256], cur[256];
    int b = blockIdx.x;
    int t = threadIdx.x;
    int s0 = ba[b], s1 = ba[b + 1];
    cnt[t] = 0;
    __syncthreads();
    for (int i = s0 + t; i < s1; i += 256)
        atomicAdd(&cnt[pr[i] >> 24], 1);
    __syncthreads();
    int c = cnt[t];
    cur[t] = c;
    __syncthreads();
    for (int off = 1; off < 256; off <<= 1) {
        int x = (t >= off) ? cur[t - off] : 0;
        __syncthreads();
        cur[t] += x;
        __syncthreads();
    }
    int excl = cur[t] - c;
    __syncthreads();
    cur[t] = s0 + excl;
    int node = (b << 8) + t;
    if (node < n) row[node] = s0 + excl;
    if (b == nb - 1 && t == 0) row[n] = nE;
    __syncthreads();
    for (int i = s0 + t; i < s1; i += 256) {
        unsigned p = pr[i];
        int slot = atomicAdd(&cur[p >> 24], 1);
        srcs[slot] = (int)(p & 0xFFFFFFu);
    }
}

// ---------------- dense compute (branch via blockIdx.y + yoff) ----------------

struct TArgs { const void *x, *ws, *wn, *bias; float *acc, *nbr; };

// acc = x @ w_self + bias ; nbr = x @ w_nbr   (x: [N,128], W: [128,16])
__global__ __launch_bounds__(256) void k_transform1(
    TArgs a0, TArgs a1, int n, int yoff, const int* __restrict__ flag)
{
    TArgs A = (blockIdx.y + yoff) ? a1 : a0;
    const int isf32 = *flag;
    __shared__ float Wl[F_IN][32];  // cols 0..15 = w_self, 16..31 = w_nbr
    for (int idx = threadIdx.x; idx < F_IN * 32; idx += 256) {
        int k = idx >> 5, j = idx & 31;
        Wl[k][j] = (j < 16) ? ldf(A.ws, isf32, k * 16 + j)
                            : ldf(A.wn, isf32, k * 16 + (j - 16));
    }
    __syncthreads();
    int node = blockIdx.x * 256 + threadIdx.x;
    if (node >= n) return;
    float acc[32];
#pragma unroll
    for (int j = 0; j < 16; ++j) acc[j] = ldf(A.bias, isf32, j);
#pragma unroll
    for (int j = 16; j < 32; ++j) acc[j] = 0.f;

    if (isf32) {
        const float4* xrow = (const float4*)((const float*)A.x + (size_t)node * F_IN);
        for (int kk = 0; kk < 32; ++kk) {
            float4 q = xrow[kk];
            float xs[4] = {q.x, q.y, q.z, q.w};
            int kbase = kk * 4;
#pragma unroll
            for (int h = 0; h < 4; ++h) {
                float xv = xs[h];
                const float* wrow = &Wl[kbase + h][0];
#pragma unroll
                for (int j = 0; j < 32; ++j) acc[j] += xv * wrow[j];
            }
        }
    } else {
        const uint4* xrow = (const uint4*)((const unsigned short*)A.x + (size_t)node * F_IN);
        for (int kk = 0; kk < 16; ++kk) {
            uint4 q = xrow[kk];
            float xs[8] = {bflo(q.x), bfhi(q.x), bflo(q.y), bfhi(q.y),
                           bflo(q.z), bfhi(q.z), bflo(q.w), bfhi(q.w)};
            int kbase = kk * 8;
#pragma unroll
            for (int h = 0; h < 8; ++h) {
                float xv = xs[h];
                const float* wrow = &Wl[kbase + h][0];
#pragma unroll
                for (int j = 0; j < 32; ++j) acc[j] += xv * wrow[j];
            }
        }
    }
    float4* a4 = (float4*)(A.acc + (size_t)node * 16);
    float4* n4 = (float4*)(A.nbr + (size_t)node * 16);
#pragma unroll
    for (int t = 0; t < 4; ++t) {
        a4[t] = make_float4(acc[4 * t], acc[4 * t + 1], acc[4 * t + 2], acc[4 * t + 3]);
        n4[t] = make_float4(acc[16 + 4 * t], acc[17 + 4 * t], acc[18 + 4 * t], acc[19 + 4 * t]);
    }
}

struct GArgs { const int *row, *srcs; const float* val; float* out; };

// out[node,0:16] = (selfmode ? out[node] : 0) + sum_{neighbors} val[s]
__global__ __launch_bounds__(256) void k_gather16(
    GArgs g0, GArgs g1, int n, int selfmode, int yoff)
{
    GArgs G = (blockIdx.y + yoff) ? g1 : g0;
    int t = blockIdx.x * 256 + threadIdx.x;
    int node = t >> 2;
    if (node >= n) return;
    int c = (t & 3) << 2;
    int rs = G.row[node], re = G.row[node + 1];
    float4 sum = make_float4(0.f, 0.f, 0.f, 0.f);
    if (selfmode) sum = *(const float4*)(G.out + ((size_t)node << 4) + c);
    int j = rs;
    for (; j + 4 <= re; j += 4) {
        int s0 = G.srcs[j], s1 = G.srcs[j + 1], s2 = G.srcs[j + 2], s3 = G.srcs[j + 3];
        float4 v0 = *(const float4*)(G.val + ((size_t)s0 << 4) + c);
        float4 v1 = *(const float4*)(G.val + ((size_t)s1 << 4) + c);
        float4 v2 = *(const float4*)(G.val + ((size_t)s2 << 4) + c);
        float4 v3 = *(const float4*)(G.val + ((size_t)s3 << 4) + c);
        sum.x += v0.x + v1.x + v2.x + v3.x;
        sum.y += v0.y + v1.y + v2.y + v3.y;
        sum.z += v0.z + v1.z + v2.z + v3.z;
        sum.w += v0.w + v1.w + v2.w + v3.w;
    }
    for (; j < re; ++j) {
        int s = G.srcs[j];
        const float4 v = *(const float4*)(G.val + ((size_t)s << 4) + c);
        sum.x += v.x; sum.y += v.y; sum.z += v.z; sum.w += v.w;
    }
    *(float4*)(G.out + ((size_t)node << 4) + c) = sum;
}

struct L2aArgs { const float* h1; float* p1; const void *w2s, *b2; int colOff; };

// p1 = relu(h1); mol[:,off:off+50) = p1 @ w2s + b2
__global__ __launch_bounds__(256) void k_layer2a(
    L2aArgs a0, L2aArgs a1, float* __restrict__ mol, int n, int yoff,
    const int* __restrict__ flag)
{
    L2aArgs A = (blockIdx.y + yoff) ? a1 : a0;
    const int isf32 = *flag;
    __shared__ float Ws[16][50];
    __shared__ float Bs[50];
    for (int idx = threadIdx.x; idx < 800; idx += 256)
        Ws[idx / 50][idx % 50] = ldf(A.w2s, isf32, idx);
    if (threadIdx.x < 50) Bs[threadIdx.x] = ldf(A.b2, isf32, threadIdx.x);
    __syncthreads();
    int node = blockIdx.x * 256 + threadIdx.x;
    if (node >= n) return;
    float p[16];
    const float4* row = (const float4*)(A.h1 + (size_t)node * 16);
#pragma unroll
    for (int t = 0; t < 4; ++t) {
        float4 v = row[t];
        p[4 * t] = fmaxf(v.x, 0.f); p[4 * t + 1] = fmaxf(v.y, 0.f);
        p[4 * t + 2] = fmaxf(v.z, 0.f); p[4 * t + 3] = fmaxf(v.w, 0.f);
    }
    float4* pout = (float4*)(A.p1 + (size_t)node * 16);
#pragma unroll
    for (int t = 0; t < 4; ++t)
        pout[t] = make_float4(p[4 * t], p[4 * t + 1], p[4 * t + 2], p[4 * t + 3]);
    float acc[50];
#pragma unroll
    for (int j = 0; j < 50; ++j) acc[j] = Bs[j];
#pragma unroll
    for (int k = 0; k < 16; ++k) {
        float pv = p[k];
#pragma unroll
        for (int j = 0; j < 50; ++j) acc[j] += pv * Ws[k][j];
    }
    float* o = mol + (size_t)node * 100 + A.colOff;
#pragma unroll
    for (int j = 0; j < 50; ++j) o[j] = acc[j];
}

struct L2bArgs { const float* agg; const void* w2n; int colOff; };

// mol[:, colOff..colOff+50) += agg @ w2n
__global__ __launch_bounds__(256) void k_layer2b(
    L2bArgs a0, L2bArgs a1, float* __restrict__ mol, int n, int yoff,
    const int* __restrict__ flag)
{
    L2bArgs A = (blockIdx.y + yoff) ? a1 : a0;
    const int isf32 = *flag;
    __shared__ float Ws[16][50];
    for (int idx = threadIdx.x; idx < 800; idx += 256)
        Ws[idx / 50][idx % 50] = ldf(A.w2n, isf32, idx);
    __syncthreads();
    int node = blockIdx.x * 256 + threadIdx.x;
    if (node >= n) return;
    float g[16];
    const float4* grow = (const float4*)(A.agg + (size_t)node * 16);
#pragma unroll
    for (int t = 0; t < 4; ++t) {
        float4 v = grow[t];
        g[4 * t] = v.x; g[4 * t + 1] = v.y; g[4 * t + 2] = v.z; g[4 * t + 3] = v.w;
    }
    float* o = mol + (size_t)node * 100 + A.colOff;
    float acc[50];
#pragma unroll
    for (int j = 0; j < 50; ++j) acc[j] = o[j];
#pragma unroll
    for (int k = 0; k < 16; ++k) {
        float gv = g[k];
#pragma unroll
        for (int j = 0; j < 50; ++j) acc[j] += gv * Ws[k][j];
    }
#pragma unroll
    for (int j = 0; j < 50; ++j) o[j] = acc[j];
}

// head: fp = relu(mol@w_in+b_in); h = relu([fp,action]@w_hid+b_hid); out = h@w_out+b_out
// fp computed in two 30-wide halves to avoid register spill (R4).
__global__ __launch_bounds__(256) void k_head(
    const float* __restrict__ mol, const void* __restrict__ action,
    const void* __restrict__ w_in, const void* __restrict__ b_in,
    const void* __restrict__ w_hid, const void* __restrict__ b_hid,
    const void* __restrict__ w_out, const void* __restrict__ b_out,
    void* __restrict__ out, int n, const int* __restrict__ flag)
{
    const int isf32 = *flag;
    __shared__ float Win[100 * 60];
    __shared__ float Whid[70 * 10];
    __shared__ float Bin[60], Bhid[10], Wout[10];
    __shared__ float Bout;
    for (int idx = threadIdx.x; idx < 6000; idx += 256) Win[idx] = ldf(w_in, isf32, idx);
    for (int idx = threadIdx.x; idx < 700; idx += 256) Whid[idx] = ldf(w_hid, isf32, idx);
    if (threadIdx.x < 60) Bin[threadIdx.x] = ldf(b_in, isf32, threadIdx.x);
    if (threadIdx.x < 10) {
        Bhid[threadIdx.x] = ldf(b_hid, isf32, threadIdx.x);
        Wout[threadIdx.x] = ldf(w_out, isf32, threadIdx.x);
    }
    if (threadIdx.x == 0) Bout = ldf(b_out, isf32, 0);
    __syncthreads();
    int node = blockIdx.x * 256 + threadIdx.x;
    if (node >= n) return;

    const float4* m4 = (const float4*)(mol + (size_t)node * 100);
    float h[10];
#pragma unroll
    for (int j = 0; j < 10; ++j) h[j] = Bhid[j];

#pragma unroll
    for (int half = 0; half < 2; ++half) {
        const int jo = half * 30;
        float fp[30];
#pragma unroll
        for (int j = 0; j < 30; ++j) fp[j] = Bin[jo + j];
        for (int kk = 0; kk < 25; ++kk) {
            float4 q = m4[kk];
            float xs[4] = {q.x, q.y, q.z, q.w};
#pragma unroll
            for (int hh = 0; hh < 4; ++hh) {
                float m = xs[hh];
                const float* w = &Win[(kk * 4 + hh) * 60 + jo];
#pragma unroll
                for (int j = 0; j < 30; ++j) fp[j] += m * w[j];
            }
        }
#pragma unroll
        for (int k = 0; k < 30; ++k) {
            float v = fmaxf(fp[k], 0.f);
            const float* w = &Whid[(jo + k) * 10];
#pragma unroll
            for (int j = 0; j < 10; ++j) h[j] += v * w[j];
        }
    }
#pragma unroll
    for (int k = 0; k < 10; ++k) {
        float v = ldf(action, isf32, (size_t)node * 10 + k);
        const float* w = &Whid[(60 + k) * 10];
#pragma unroll
        for (int j = 0; j < 10; ++j) h[j] += v * w[j];
    }
    float o = Bout;
#pragma unroll
    for (int j = 0; j < 10; ++j) o += fmaxf(h[j], 0.f) * Wout[j];
    if (isf32) ((float*)out)[node] = o;
    else       ((unsigned short*)out)[node] = f2bf(o);
}

extern "C" void kernel_launch(void* const* d_in, const int* in_sizes, int n_in,
                              void* d_out, int out_size, void* d_ws, size_t ws_size,
                              hipStream_t stream)
{
    const void* px   = d_in[0];
    const int*  pe   = (const int*)d_in[1];
    const void* lx   = d_in[2];
    const int*  le   = (const int*)d_in[3];
    const void* act  = d_in[4];
    const void* wp1s = d_in[5];
    const void* wp1n = d_in[6];
    const void* bp1  = d_in[7];
    const void* wp2s = d_in[8];
    const void* wp2n = d_in[9];
    const void* bp2  = d_in[10];
    const void* wl1s = d_in[11];
    const void* wl1n = d_in[12];
    const void* bl1  = d_in[13];
    const void* wl2s = d_in[14];
    const void* wl2n = d_in[15];
    const void* bl2  = d_in[16];
    const void* w_in  = d_in[17];
    const void* b_in  = d_in[18];
    const void* w_hid = d_in[19];
    const void* b_hid = d_in[20];
    const void* w_out = d_in[21];
    const void* b_out = d_in[22];

    const int N = in_sizes[0] / F_IN;
    const int E = in_sizes[1] / 2;
    const int NB = (N + 255) >> 8;

    // header: flag(64) | cnt(2*512) | base(2*528) | cursor(2*512) = 3200 ints
    int* flag    = (int*)d_ws;
    int* cnt     = flag + 64;
    int* base    = cnt + 2 * NBMAX;
    int* cursorB = base + 2 * 528;
    int* rowP    = flag + 3200;
    int* srcsP   = rowP + (N + 64);
    int* rowL    = srcsP + E;
    int* srcsL   = rowL + (N + 64);
    float* dense = (float*)(srcsL + E);
    unsigned* pairs = (unsigned*)dense;   // 2E uints; dead before dense writes

    size_t head_bytes  = (size_t)(3200 + 2 * (N + 64) + 2 * E) * 4;
    size_t need_fused  = head_bytes + (size_t)164 * N * 4;
    const bool fused = (ws_size >= need_fused);

    float *accP, *n1P, *accL, *n1L, *mol;
    if (fused) {
        accP = dense;             n1P = accP + (size_t)N * 16;
        accL = n1P + (size_t)N * 16; n1L = accL + (size_t)N * 16;
        mol  = n1L + (size_t)N * 16;
    } else {
        accP = accL = dense;
        n1P = n1L = dense + (size_t)N * 16;
        mol  = dense + (size_t)N * 32;
    }

    const int nb = (N + 255) / 256;
    const int gb = (N * 4 + 255) / 256;
    const int bb = (E + 4095) / 4096;

    k_detect<<<1, 256, 0, stream>>>((const unsigned short*)px, 4096, flag);

    // ---- CSR build for both graphs (blockIdx.y = graph) ----
    k_zero<<<4, 256, 0, stream>>>(cnt, 2 * NBMAX);
    k_bucket_hist<<<dim3(512, 2), 256, 0, stream>>>(pe + E, le + E, cnt, E);
    k_bucket_scan<<<2, 512, 0, stream>>>(cnt, base, cursorB, NB);
    k_bucket_bin<<<dim3(bb, 2), 256, 0, stream>>>(pe, pe + E, le, le + E,
                                                  cursorB, pairs, E);
    k_bucket_fine<<<dim3(NB, 2), 256, 0, stream>>>(pairs, base, rowP, srcsP,
                                                   rowL, srcsL, N, E, NB);

    TArgs tP{px, wp1s, wp1n, bp1, accP, n1P};
    TArgs tL{lx, wl1s, wl1n, bl1, accL, n1L};
    GArgs g1P{rowP, srcsP, n1P, accP}, g1L{rowL, srcsL, n1L, accL};
    L2aArgs aP{accP, n1P, wp2s, bp2, 0}, aL{accL, n1L, wl2s, bl2, 50};
    L2bArgs bP{accP, wp2n, 0}, bL{accL, wl2n, 50};

    if (fused) {
        k_transform1<<<dim3(nb, 2), 256, 0, stream>>>(tP, tL, N, 0, flag);
        k_gather16<<<dim3(gb, 2), 256, 0, stream>>>(g1P, g1L, N, 1, 0);
        k_layer2a<<<dim3(nb, 2), 256, 0, stream>>>(aP, aL, mol, N, 0, flag);
        k_gather16<<<dim3(gb, 2), 256, 0, stream>>>(g1P, g1L, N, 0, 0);
        k_layer2b<<<dim3(nb, 2), 256, 0, stream>>>(bP, bL, mol, N, 0, flag);
    } else {
        // sequential: shared buffers, branch chains back-to-back
        k_transform1<<<nb, 256, 0, stream>>>(tP, tL, N, 0, flag);
        k_gather16<<<gb, 256, 0, stream>>>(g1P, g1L, N, 1, 0);
        k_layer2a<<<nb, 256, 0, stream>>>(aP, aL, mol, N, 0, flag);
        k_gather16<<<gb, 256, 0, stream>>>(g1P, g1L, N, 0, 0);
        k_layer2b<<<nb, 256, 0, stream>>>(bP, bL, mol, N, 0, flag);

        k_transform1<<<nb, 256, 0, stream>>>(tP, tL, N, 1, flag);
        k_gather16<<<gb, 256, 0, stream>>>(g1P, g1L, N, 1, 1);
        k_layer2a<<<nb, 256, 0, stream>>>(aP, aL, mol, N, 1, flag);
        k_gather16<<<gb, 256, 0, stream>>>(g1P, g1L, N, 0, 1);
        k_layer2b<<<nb, 256, 0, stream>>>(bP, bL, mol, N, 1, flag);
    }

    // ---- head ----
    k_head<<<nb, 256, 0, stream>>>(mol, act, w_in, b_in, w_hid, b_hid, w_out, b_out,
                                   d_out, N, flag);
}

// Round 6
// 700.959 us; speedup vs baseline: 4.2476x; 1.1302x over previous
//
#include <hip/hip_runtime.h>
#include <hip/hip_bf16.h>
#include <stdint.h>

// CriticGNN: two GraphConv branches + MLP head.
// R0: aggregate AFTER the 128->16 transform (segment_sum is linear).
// R1: runtime dtype detection (bf16 vs f32 device buffers).
// R2: CSR (counting sort by dst) + gather instead of f32 atomics.
// R3: two-level bucketed counting sort (LDS histograms, burst writes).
// R4: k_head spill fix attempt (failed - compiler re-merged), fused dispatches.
// R5: k_head spill REAL fix: cap mol-load hoisting with #pragma unroll 5
//     (spill came from 25 hoisted float4 loads, not fp[60]).
//     Gather tables in bf16 (32 B/row): 3.2 MB fits per-XCD L2; 8-deep unroll.

#define F_IN 128
#define NBMAX 512   // max coarse buckets (N <= 131072)

__device__ __forceinline__ float bf2f(unsigned short u) {
    union { unsigned int i; float f; } v; v.i = ((unsigned int)u) << 16; return v.f;
}
__device__ __forceinline__ float bflo(unsigned int u) {
    union { unsigned int i; float f; } v; v.i = u << 16; return v.f;
}
__device__ __forceinline__ float bfhi(unsigned int u) {
    union { unsigned int i; float f; } v; v.i = u & 0xffff0000u; return v.f;
}
__device__ __forceinline__ unsigned short f2bf(float f) {
    union { float f; unsigned int i; } v; v.f = f;
    unsigned int u = v.i;
    unsigned int r = (u + 0x7fffu + ((u >> 16) & 1u)) >> 16;  // RNE
    return (unsigned short)r;
}
__device__ __forceinline__ unsigned pack2bf(float a, float b) {
    return (unsigned)f2bf(a) | ((unsigned)f2bf(b) << 16);
}
__device__ __forceinline__ float ldf(const void* p, int isf32, size_t i) {
    return isf32 ? ((const float*)p)[i] : bf2f(((const unsigned short*)p)[i]);
}

__global__ __launch_bounds__(256) void k_detect(
    const unsigned short* __restrict__ x, int nProbe, int* __restrict__ flag)
{
    __shared__ int cnt;
    if (threadIdx.x == 0) cnt = 0;
    __syncthreads();
    int bad = 0;
    for (int i = threadIdx.x; i < nProbe; i += 256) {
        unsigned e = (x[i] >> 7) & 0xFFu;
        if (e >= 140u) bad++;
    }
    atomicAdd(&cnt, bad);
    __syncthreads();
    if (threadIdx.x == 0) *flag = (cnt > nProbe / 16) ? 1 : 0;
}

// ---------------- bucketed CSR build (both graphs via blockIdx.y) ----------------

__global__ __launch_bounds__(256) void k_zero(int* __restrict__ p, int n) {
    int i = blockIdx.x * 256 + threadIdx.x;
    if (i < n) p[i] = 0;
}

__global__ __launch_bounds__(256) void k_bucket_hist(
    const int* __restrict__ ed0, const int* __restrict__ ed1,
    int* __restrict__ cnt, int nE)
{
    const int* ed = blockIdx.y ? ed1 : ed0;
    int* c = cnt + blockIdx.y * NBMAX;
    __shared__ int h[NBMAX];
    for (int i = threadIdx.x; i < NBMAX; i += 256) h[i] = 0;
    __syncthreads();
    int stride = gridDim.x * 256;
    for (int e = blockIdx.x * 256 + threadIdx.x; e < nE; e += stride)
        atomicAdd(&h[ed[e] >> 8], 1);
    __syncthreads();
    for (int i = threadIdx.x; i < NBMAX; i += 256)
        if (h[i]) atomicAdd(&c[i], h[i]);
}

__global__ __launch_bounds__(512) void k_bucket_scan(
    const int* __restrict__ cnt, int* __restrict__ base,
    int* __restrict__ cursor, int nb)
{
    const int* c = cnt + blockIdx.x * NBMAX;
    int* ba = base + blockIdx.x * 528;
    int* cu = cursor + blockIdx.x * NBMAX;
    __shared__ int sh[512];
    int t = threadIdx.x;
    int v = (t < nb) ? c[t] : 0;
    sh[t] = v;
    __syncthreads();
    for (int off = 1; off < 512; off <<= 1) {
        int x = (t >= off) ? sh[t - off] : 0;
        __syncthreads();
        sh[t] += x;
        __syncthreads();
    }
    int excl = sh[t] - v;
    if (t < nb) { ba[t] = excl; cu[t] = excl; }
    if (t == nb - 1) ba[nb] = excl + v;
}

#define BIN_CH 16
__global__ __launch_bounds__(256) void k_bucket_bin(
    const int* __restrict__ es0, const int* __restrict__ ed0,
    const int* __restrict__ es1, const int* __restrict__ ed1,
    int* __restrict__ cursor, unsigned* __restrict__ pairs, int nE)
{
    const int* es = blockIdx.y ? es1 : es0;
    const int* ed = blockIdx.y ? ed1 : ed0;
    int* cur = cursor + blockIdx.y * NBMAX;
    unsigned* pr = pairs + (size_t)blockIdx.y * nE;
    __shared__ int h[NBMAX];
    for (int i = threadIdx.x; i < NBMAX; i += 256) h[i] = 0;
    __syncthreads();
    int e0 = blockIdx.x * (256 * BIN_CH);
    int s[BIN_CH], d[BIN_CH];
#pragma unroll
    for (int k = 0; k < BIN_CH; ++k) {
        int e = e0 + k * 256 + threadIdx.x;
        if (e < nE) {
            s[k] = es[e]; d[k] = ed[e];
            atomicAdd(&h[d[k] >> 8], 1);
        } else d[k] = -1;
    }
    __syncthreads();
    for (int b = threadIdx.x; b < NBMAX; b += 256) {
        int c = h[b];
        if (c) h[b] = atomicAdd(&cur[b], c);
    }
    __syncthreads();
#pragma unroll
    for (int k = 0; k < BIN_CH; ++k) {
        if (d[k] >= 0) {
            int pos = atomicAdd(&h[d[k] >> 8], 1);
            pr[pos] = ((unsigned)(d[k] & 255) << 24) | (unsigned)s[k];
        }
    }
}

__global__ __launch_bounds__(256) void k_bucket_fine(
    const unsigned* __restrict__ pairs, const int* __restrict__ base,
    int* __restrict__ row0, int* __restrict__ srcs0,
    int* __restrict__ row1, int* __restrict__ srcs1,
    int n, int nE, int nb)
{
    const unsigned* pr = pairs + (size_t)blockIdx.y * nE;
    const int* ba = base + blockIdx.y * 528;
    int* row = blockIdx.y ? row1 : row0;
    int* srcs = blockIdx.y ? srcs1 : srcs0;
    __shared__ int cnt[256], cur[256];
    int b = blockIdx.x;
    int t = threadIdx.x;
    int s0 = ba[b], s1 = ba[b + 1];
    cnt[t] = 0;
    __syncthreads();
    for (int i = s0 + t; i < s1; i += 256)
        atomicAdd(&cnt[pr[i] >> 24], 1);
    __syncthreads();
    int c = cnt[t];
    cur[t] = c;
    __syncthreads();
    for (int off = 1; off < 256; off <<= 1) {
        int x = (t >= off) ? cur[t - off] : 0;
        __syncthreads();
        cur[t] += x;
        __syncthreads();
    }
    int excl = cur[t] - c;
    __syncthreads();
    cur[t] = s0 + excl;
    int node = (b << 8) + t;
    if (node < n) row[node] = s0 + excl;
    if (b == nb - 1 && t == 0) row[n] = nE;
    __syncthreads();
    for (int i = s0 + t; i < s1; i += 256) {
        unsigned p = pr[i];
        int slot = atomicAdd(&cur[p >> 24], 1);
        srcs[slot] = (int)(p & 0xFFFFFFu);
    }
}

// ---------------- dense compute (branch via blockIdx.y + yoff) ----------------

struct TArgs { const void *x, *ws, *wn, *bias; float* acc; void* nbr; };

// acc = x @ w_self + bias (f32); nbr = x @ w_nbr (bf16x16 row, 32 B/node)
__global__ __launch_bounds__(256) void k_transform1(
    TArgs a0, TArgs a1, int n, int yoff, const int* __restrict__ flag)
{
    TArgs A = (blockIdx.y + yoff) ? a1 : a0;
    const int isf32 = *flag;
    __shared__ float Wl[F_IN][32];  // cols 0..15 = w_self, 16..31 = w_nbr
    for (int idx = threadIdx.x; idx < F_IN * 32; idx += 256) {
        int k = idx >> 5, j = idx & 31;
        Wl[k][j] = (j < 16) ? ldf(A.ws, isf32, k * 16 + j)
                            : ldf(A.wn, isf32, k * 16 + (j - 16));
    }
    __syncthreads();
    int node = blockIdx.x * 256 + threadIdx.x;
    if (node >= n) return;
    float acc[32];
#pragma unroll
    for (int j = 0; j < 16; ++j) acc[j] = ldf(A.bias, isf32, j);
#pragma unroll
    for (int j = 16; j < 32; ++j) acc[j] = 0.f;

    if (isf32) {
        const float4* xrow = (const float4*)((const float*)A.x + (size_t)node * F_IN);
        for (int kk = 0; kk < 32; ++kk) {
            float4 q = xrow[kk];
            float xs[4] = {q.x, q.y, q.z, q.w};
            int kbase = kk * 4;
#pragma unroll
            for (int h = 0; h < 4; ++h) {
                float xv = xs[h];
                const float* wrow = &Wl[kbase + h][0];
#pragma unroll
                for (int j = 0; j < 32; ++j) acc[j] += xv * wrow[j];
            }
        }
    } else {
        const uint4* xrow = (const uint4*)((const unsigned short*)A.x + (size_t)node * F_IN);
        for (int kk = 0; kk < 16; ++kk) {
            uint4 q = xrow[kk];
            float xs[8] = {bflo(q.x), bfhi(q.x), bflo(q.y), bfhi(q.y),
                           bflo(q.z), bfhi(q.z), bflo(q.w), bfhi(q.w)};
            int kbase = kk * 8;
#pragma unroll
            for (int h = 0; h < 8; ++h) {
                float xv = xs[h];
                const float* wrow = &Wl[kbase + h][0];
#pragma unroll
                for (int j = 0; j < 32; ++j) acc[j] += xv * wrow[j];
            }
        }
    }
    float4* a4 = (float4*)(A.acc + (size_t)node * 16);
#pragma unroll
    for (int t = 0; t < 4; ++t)
        a4[t] = make_float4(acc[4 * t], acc[4 * t + 1], acc[4 * t + 2], acc[4 * t + 3]);
    unsigned short* nrow = (unsigned short*)A.nbr + ((size_t)node << 4);
    *(uint4*)nrow = make_uint4(pack2bf(acc[16], acc[17]), pack2bf(acc[18], acc[19]),
                               pack2bf(acc[20], acc[21]), pack2bf(acc[22], acc[23]));
    *(uint4*)(nrow + 8) = make_uint4(pack2bf(acc[24], acc[25]), pack2bf(acc[26], acc[27]),
                                     pack2bf(acc[28], acc[29]), pack2bf(acc[30], acc[31]));
}

struct GArgs { const int *row, *srcs; const void* val; float* out; };

// out[node,0:16] (f32) = (selfmode ? out[node] : 0) + sum_{nbrs} bf16row val[s]
// 4 lanes/node; each lane covers 4 bf16 (8 B load). 8-deep unrolled pipeline.
__global__ __launch_bounds__(256) void k_gather16(
    GArgs g0, GArgs g1, int n, int selfmode, int yoff)
{
    GArgs G = (blockIdx.y + yoff) ? g1 : g0;
    int t = blockIdx.x * 256 + threadIdx.x;
    int node = t >> 2;
    if (node >= n) return;
    int c = (t & 3) << 2;   // element offset (4 bf16 per lane)
    const unsigned short* vb = (const unsigned short*)G.val;
    int rs = G.row[node], re = G.row[node + 1];
    float4 sum = make_float4(0.f, 0.f, 0.f, 0.f);
    if (selfmode) sum = *(const float4*)(G.out + ((size_t)node << 4) + c);
    int j = rs;
    for (; j + 8 <= re; j += 8) {
        int s[8];
        uint2 v[8];
#pragma unroll
        for (int u = 0; u < 8; ++u) s[u] = G.srcs[j + u];
#pragma unroll
        for (int u = 0; u < 8; ++u)
            v[u] = *(const uint2*)(vb + (((size_t)s[u]) << 4) + c);
#pragma unroll
        for (int u = 0; u < 8; ++u) {
            sum.x += bflo(v[u].x); sum.y += bfhi(v[u].x);
            sum.z += bflo(v[u].y); sum.w += bfhi(v[u].y);
        }
    }
    for (; j < re; ++j) {
        uint2 v = *(const uint2*)(vb + (((size_t)G.srcs[j]) << 4) + c);
        sum.x += bflo(v.x); sum.y += bfhi(v.x);
        sum.z += bflo(v.y); sum.w += bfhi(v.y);
    }
    *(float4*)(G.out + ((size_t)node << 4) + c) = sum;
}

struct L2aArgs { const float* h1; void* p1; const void *w2s, *b2; int colOff; };

// p = relu(h1); mol[:,off:off+50) = p @ w2s + b2; p1 (bf16 row) for gather 2
__global__ __launch_bounds__(256) void k_layer2a(
    L2aArgs a0, L2aArgs a1, float* __restrict__ mol, int n, int yoff,
    const int* __restrict__ flag)
{
    L2aArgs A = (blockIdx.y + yoff) ? a1 : a0;
    const int isf32 = *flag;
    __shared__ float Ws[16][50];
    __shared__ float Bs[50];
    for (int idx = threadIdx.x; idx < 800; idx += 256)
        Ws[idx / 50][idx % 50] = ldf(A.w2s, isf32, idx);
    if (threadIdx.x < 50) Bs[threadIdx.x] = ldf(A.b2, isf32, threadIdx.x);
    __syncthreads();
    int node = blockIdx.x * 256 + threadIdx.x;
    if (node >= n) return;
    float p[16];
    const float4* row = (const float4*)(A.h1 + (size_t)node * 16);
#pragma unroll
    for (int t = 0; t < 4; ++t) {
        float4 v = row[t];
        p[4 * t] = fmaxf(v.x, 0.f); p[4 * t + 1] = fmaxf(v.y, 0.f);
        p[4 * t + 2] = fmaxf(v.z, 0.f); p[4 * t + 3] = fmaxf(v.w, 0.f);
    }
    unsigned short* prow = (unsigned short*)A.p1 + ((size_t)node << 4);
    *(uint4*)prow = make_uint4(pack2bf(p[0], p[1]), pack2bf(p[2], p[3]),
                               pack2bf(p[4], p[5]), pack2bf(p[6], p[7]));
    *(uint4*)(prow + 8) = make_uint4(pack2bf(p[8], p[9]), pack2bf(p[10], p[11]),
                                     pack2bf(p[12], p[13]), pack2bf(p[14], p[15]));
    float acc[50];
#pragma unroll
    for (int j = 0; j < 50; ++j) acc[j] = Bs[j];
#pragma unroll
    for (int k = 0; k < 16; ++k) {
        float pv = p[k];
#pragma unroll
        for (int j = 0; j < 50; ++j) acc[j] += pv * Ws[k][j];
    }
    float* o = mol + (size_t)node * 100 + A.colOff;
#pragma unroll
    for (int j = 0; j < 50; ++j) o[j] = acc[j];
}

struct L2bArgs { const float* agg; const void* w2n; int colOff; };

// mol[:, colOff..colOff+50) += agg @ w2n
__global__ __launch_bounds__(256) void k_layer2b(
    L2bArgs a0, L2bArgs a1, float* __restrict__ mol, int n, int yoff,
    const int* __restrict__ flag)
{
    L2bArgs A = (blockIdx.y + yoff) ? a1 : a0;
    const int isf32 = *flag;
    __shared__ float Ws[16][50];
    for (int idx = threadIdx.x; idx < 800; idx += 256)
        Ws[idx / 50][idx % 50] = ldf(A.w2n, isf32, idx);
    __syncthreads();
    int node = blockIdx.x * 256 + threadIdx.x;
    if (node >= n) return;
    float g[16];
    const float4* grow = (const float4*)(A.agg + (size_t)node * 16);
#pragma unroll
    for (int t = 0; t < 4; ++t) {
        float4 v = grow[t];
        g[4 * t] = v.x; g[4 * t + 1] = v.y; g[4 * t + 2] = v.z; g[4 * t + 3] = v.w;
    }
    float* o = mol + (size_t)node * 100 + A.colOff;
    float acc[50];
#pragma unroll
    for (int j = 0; j < 50; ++j) acc[j] = o[j];
#pragma unroll
    for (int k = 0; k < 16; ++k) {
        float gv = g[k];
#pragma unroll
        for (int j = 0; j < 50; ++j) acc[j] += gv * Ws[k][j];
    }
#pragma unroll
    for (int j = 0; j < 50; ++j) o[j] = acc[j];
}

// head: fp = relu(mol@w_in+b_in); h = relu([fp,action]@w_hid+b_hid); out = h@w_out+b_out
// fp[60] lives in regs (~60 VGPR); #pragma unroll 5 on the kk loop bounds the
// number of in-flight mol float4 loads (R4/R5: full hoist of 25 loads spilled).
__global__ __launch_bounds__(256) void k_head(
    const float* __restrict__ mol, const void* __restrict__ action,
    const void* __restrict__ w_in, const void* __restrict__ b_in,
    const void* __restrict__ w_hid, const void* __restrict__ b_hid,
    const void* __restrict__ w_out, const void* __restrict__ b_out,
    void* __restrict__ out, int n, const int* __restrict__ flag)
{
    const int isf32 = *flag;
    __shared__ float Win[100 * 60];
    __shared__ float Whid[70 * 10];
    __shared__ float Bin[60], Bhid[10], Wout[10];
    __shared__ float Bout;
    for (int idx = threadIdx.x; idx < 6000; idx += 256) Win[idx] = ldf(w_in, isf32, idx);
    for (int idx = threadIdx.x; idx < 700; idx += 256) Whid[idx] = ldf(w_hid, isf32, idx);
    if (threadIdx.x < 60) Bin[threadIdx.x] = ldf(b_in, isf32, threadIdx.x);
    if (threadIdx.x < 10) {
        Bhid[threadIdx.x] = ldf(b_hid, isf32, threadIdx.x);
        Wout[threadIdx.x] = ldf(w_out, isf32, threadIdx.x);
    }
    if (threadIdx.x == 0) Bout = ldf(b_out, isf32, 0);
    __syncthreads();
    int node = blockIdx.x * 256 + threadIdx.x;
    if (node >= n) return;

    const float4* m4 = (const float4*)(mol + (size_t)node * 100);
    float fp[60];
#pragma unroll
    for (int j = 0; j < 60; ++j) fp[j] = Bin[j];
#pragma unroll 5
    for (int kk = 0; kk < 25; ++kk) {
        float4 q = m4[kk];
        float xs[4] = {q.x, q.y, q.z, q.w};
#pragma unroll
        for (int hh = 0; hh < 4; ++hh) {
            float m = xs[hh];
            const float* w = &Win[(kk * 4 + hh) * 60];
#pragma unroll
            for (int j = 0; j < 60; ++j) fp[j] += m * w[j];
        }
    }
    float h[10];
#pragma unroll
    for (int j = 0; j < 10; ++j) h[j] = Bhid[j];
#pragma unroll
    for (int k = 0; k < 60; ++k) {
        float v = fmaxf(fp[k], 0.f);
        const float* w = &Whid[k * 10];
#pragma unroll
        for (int j = 0; j < 10; ++j) h[j] += v * w[j];
    }
#pragma unroll
    for (int k = 0; k < 10; ++k) {
        float v = ldf(action, isf32, (size_t)node * 10 + k);
        const float* w = &Whid[(60 + k) * 10];
#pragma unroll
        for (int j = 0; j < 10; ++j) h[j] += v * w[j];
    }
    float o = Bout;
#pragma unroll
    for (int j = 0; j < 10; ++j) o += fmaxf(h[j], 0.f) * Wout[j];
    if (isf32) ((float*)out)[node] = o;
    else       ((unsigned short*)out)[node] = f2bf(o);
}

extern "C" void kernel_launch(void* const* d_in, const int* in_sizes, int n_in,
                              void* d_out, int out_size, void* d_ws, size_t ws_size,
                              hipStream_t stream)
{
    const void* px   = d_in[0];
    const int*  pe   = (const int*)d_in[1];
    const void* lx   = d_in[2];
    const int*  le   = (const int*)d_in[3];
    const void* act  = d_in[4];
    const void* wp1s = d_in[5];
    const void* wp1n = d_in[6];
    const void* bp1  = d_in[7];
    const void* wp2s = d_in[8];
    const void* wp2n = d_in[9];
    const void* bp2  = d_in[10];
    const void* wl1s = d_in[11];
    const void* wl1n = d_in[12];
    const void* bl1  = d_in[13];
    const void* wl2s = d_in[14];
    const void* wl2n = d_in[15];
    const void* bl2  = d_in[16];
    const void* w_in  = d_in[17];
    const void* b_in  = d_in[18];
    const void* w_hid = d_in[19];
    const void* b_hid = d_in[20];
    const void* w_out = d_in[21];
    const void* b_out = d_in[22];

    const int N = in_sizes[0] / F_IN;
    const int E = in_sizes[1] / 2;
    const int NB = (N + 255) >> 8;

    // header: flag(64) | cnt(2*512) | base(2*528) | cursor(2*512) = 3200 ints
    int* flag    = (int*)d_ws;
    int* cnt     = flag + 64;
    int* base    = cnt + 2 * NBMAX;
    int* cursorB = base + 2 * 528;
    int* rowP    = flag + 3200;
    int* srcsP   = rowP + (N + 64);
    int* rowL    = srcsP + E;
    int* srcsL   = rowL + (N + 64);
    float* dense = (float*)(srcsL + E);
    unsigned* pairs = (unsigned*)dense;   // 2E uints; dead before dense writes

    size_t head_bytes  = (size_t)(3200 + 2 * (N + 64) + 2 * E) * 4;
    size_t need_fused  = head_bytes + (size_t)164 * N * 4;
    const bool fused = (ws_size >= need_fused);

    // acc: f32 16/node; n1: bf16 16/node (32 B) but reserve f32-sized slots
    float *accP, *accL, *mol;
    void *n1P, *n1L;
    if (fused) {
        accP = dense;                       n1P = (void*)(accP + (size_t)N * 16);
        accL = (float*)n1P + (size_t)N * 16; n1L = (void*)(accL + (size_t)N * 16);
        mol  = (float*)n1L + (size_t)N * 16;
    } else {
        accP = accL = dense;
        n1P = n1L = (void*)(dense + (size_t)N * 16);
        mol  = dense + (size_t)N * 32;
    }

    const int nb = (N + 255) / 256;
    const int gb = (N * 4 + 255) / 256;
    const int bb = (E + 4095) / 4096;

    k_detect<<<1, 256, 0, stream>>>((const unsigned short*)px, 4096, flag);

    // ---- CSR build for both graphs (blockIdx.y = graph) ----
    k_zero<<<4, 256, 0, stream>>>(cnt, 2 * NBMAX);
    k_bucket_hist<<<dim3(512, 2), 256, 0, stream>>>(pe + E, le + E, cnt, E);
    k_bucket_scan<<<2, 512, 0, stream>>>(cnt, base, cursorB, NB);
    k_bucket_bin<<<dim3(bb, 2), 256, 0, stream>>>(pe, pe + E, le, le + E,
                                                  cursorB, pairs, E);
    k_bucket_fine<<<dim3(NB, 2), 256, 0, stream>>>(pairs, base, rowP, srcsP,
                                                   rowL, srcsL, N, E, NB);

    TArgs tP{px, wp1s, wp1n, bp1, accP, n1P};
    TArgs tL{lx, wl1s, wl1n, bl1, accL, n1L};
    GArgs g1P{rowP, srcsP, n1P, accP}, g1L{rowL, srcsL, n1L, accL};
    L2aArgs aP{accP, n1P, wp2s, bp2, 0}, aL{accL, n1L, wl2s, bl2, 50};
    L2bArgs bP{accP, wp2n, 0}, bL{accL, wl2n, 50};

    if (fused) {
        k_transform1<<<dim3(nb, 2), 256, 0, stream>>>(tP, tL, N, 0, flag);
        k_gather16<<<dim3(gb, 2), 256, 0, stream>>>(g1P, g1L, N, 1, 0);
        k_layer2a<<<dim3(nb, 2), 256, 0, stream>>>(aP, aL, mol, N, 0, flag);
        k_gather16<<<dim3(gb, 2), 256, 0, stream>>>(g1P, g1L, N, 0, 0);
        k_layer2b<<<dim3(nb, 2), 256, 0, stream>>>(bP, bL, mol, N, 0, flag);
    } else {
        k_transform1<<<nb, 256, 0, stream>>>(tP, tL, N, 0, flag);
        k_gather16<<<gb, 256, 0, stream>>>(g1P, g1L, N, 1, 0);
        k_layer2a<<<nb, 256, 0, stream>>>(aP, aL, mol, N, 0, flag);
        k_gather16<<<gb, 256, 0, stream>>>(g1P, g1L, N, 0, 0);
        k_layer2b<<<nb, 256, 0, stream>>>(bP, bL, mol, N, 0, flag);

        k_transform1<<<nb, 256, 0, stream>>>(tP, tL, N, 1, flag);
        k_gather16<<<gb, 256, 0, stream>>>(g1P, g1L, N, 1, 1);
        k_layer2a<<<nb, 256, 0, stream>>>(aP, aL, mol, N, 1, flag);
        k_gather16<<<gb, 256, 0, stream>>>(g1P, g1L, N, 0, 1);
        k_layer2b<<<nb, 256, 0, stream>>>(bP, bL, mol, N, 1, flag);
    }

    // ---- head ----
    k_head<<<nb, 256, 0, stream>>>(mol, act, w_in, b_in, w_hid, b_hid, w_out, b_out,
                                   d_out, N, flag);
}

// Round 7
// 654.452 us; speedup vs baseline: 4.5494x; 1.0711x over previous
//
#include <hip/hip_runtime.h>
#include <hip/hip_bf16.h>
#include <stdint.h>

// CriticGNN: two GraphConv branches + MLP head.
// R0: aggregate AFTER the 128->16 transform (segment_sum is linear).
// R1: runtime dtype detection (bf16 vs f32 device buffers).
// R2: CSR (counting sort by dst) + gather instead of f32 atomics.
// R3: two-level bucketed counting sort (LDS histograms, burst writes).
// R4/R5: k_head spill unfixed by pragmas (compiler hoists 25 float4 loads).
// R6: k_head restructured: 4 lanes/node, fp[15]/lane + __shfl_xor butterfly
//     for h[10] -> register pressure structurally bounded (~60 VGPR).
//     Gathers un-fused: one graph per dispatch so the 3.2 MB bf16 table
//     fits a single XCD's 4 MB L2 (fused = 6.4 MB working set -> thrash).

#define F_IN 128
#define NBMAX 512   // max coarse buckets (N <= 131072)

__device__ __forceinline__ float bf2f(unsigned short u) {
    union { unsigned int i; float f; } v; v.i = ((unsigned int)u) << 16; return v.f;
}
__device__ __forceinline__ float bflo(unsigned int u) {
    union { unsigned int i; float f; } v; v.i = u << 16; return v.f;
}
__device__ __forceinline__ float bfhi(unsigned int u) {
    union { unsigned int i; float f; } v; v.i = u & 0xffff0000u; return v.f;
}
__device__ __forceinline__ unsigned short f2bf(float f) {
    union { float f; unsigned int i; } v; v.f = f;
    unsigned int u = v.i;
    unsigned int r = (u + 0x7fffu + ((u >> 16) & 1u)) >> 16;  // RNE
    return (unsigned short)r;
}
__device__ __forceinline__ unsigned pack2bf(float a, float b) {
    return (unsigned)f2bf(a) | ((unsigned)f2bf(b) << 16);
}
__device__ __forceinline__ float ldf(const void* p, int isf32, size_t i) {
    return isf32 ? ((const float*)p)[i] : bf2f(((const unsigned short*)p)[i]);
}

__global__ __launch_bounds__(256) void k_detect(
    const unsigned short* __restrict__ x, int nProbe, int* __restrict__ flag)
{
    __shared__ int cnt;
    if (threadIdx.x == 0) cnt = 0;
    __syncthreads();
    int bad = 0;
    for (int i = threadIdx.x; i < nProbe; i += 256) {
        unsigned e = (x[i] >> 7) & 0xFFu;
        if (e >= 140u) bad++;
    }
    atomicAdd(&cnt, bad);
    __syncthreads();
    if (threadIdx.x == 0) *flag = (cnt > nProbe / 16) ? 1 : 0;
}

// ---------------- bucketed CSR build (both graphs via blockIdx.y) ----------------

__global__ __launch_bounds__(256) void k_zero(int* __restrict__ p, int n) {
    int i = blockIdx.x * 256 + threadIdx.x;
    if (i < n) p[i] = 0;
}

__global__ __launch_bounds__(256) void k_bucket_hist(
    const int* __restrict__ ed0, const int* __restrict__ ed1,
    int* __restrict__ cnt, int nE)
{
    const int* ed = blockIdx.y ? ed1 : ed0;
    int* c = cnt + blockIdx.y * NBMAX;
    __shared__ int h[NBMAX];
    for (int i = threadIdx.x; i < NBMAX; i += 256) h[i] = 0;
    __syncthreads();
    int stride = gridDim.x * 256;
    for (int e = blockIdx.x * 256 + threadIdx.x; e < nE; e += stride)
        atomicAdd(&h[ed[e] >> 8], 1);
    __syncthreads();
    for (int i = threadIdx.x; i < NBMAX; i += 256)
        if (h[i]) atomicAdd(&c[i], h[i]);
}

__global__ __launch_bounds__(512) void k_bucket_scan(
    const int* __restrict__ cnt, int* __restrict__ base,
    int* __restrict__ cursor, int nb)
{
    const int* c = cnt + blockIdx.x * NBMAX;
    int* ba = base + blockIdx.x * 528;
    int* cu = cursor + blockIdx.x * NBMAX;
    __shared__ int sh[512];
    int t = threadIdx.x;
    int v = (t < nb) ? c[t] : 0;
    sh[t] = v;
    __syncthreads();
    for (int off = 1; off < 512; off <<= 1) {
        int x = (t >= off) ? sh[t - off] : 0;
        __syncthreads();
        sh[t] += x;
        __syncthreads();
    }
    int excl = sh[t] - v;
    if (t < nb) { ba[t] = excl; cu[t] = excl; }
    if (t == nb - 1) ba[nb] = excl + v;
}

#define BIN_CH 16
__global__ __launch_bounds__(256) void k_bucket_bin(
    const int* __restrict__ es0, const int* __restrict__ ed0,
    const int* __restrict__ es1, const int* __restrict__ ed1,
    int* __restrict__ cursor, unsigned* __restrict__ pairs, int nE)
{
    const int* es = blockIdx.y ? es1 : es0;
    const int* ed = blockIdx.y ? ed1 : ed0;
    int* cur = cursor + blockIdx.y * NBMAX;
    unsigned* pr = pairs + (size_t)blockIdx.y * nE;
    __shared__ int h[NBMAX];
    for (int i = threadIdx.x; i < NBMAX; i += 256) h[i] = 0;
    __syncthreads();
    int e0 = blockIdx.x * (256 * BIN_CH);
    int s[BIN_CH], d[BIN_CH];
#pragma unroll
    for (int k = 0; k < BIN_CH; ++k) {
        int e = e0 + k * 256 + threadIdx.x;
        if (e < nE) {
            s[k] = es[e]; d[k] = ed[e];
            atomicAdd(&h[d[k] >> 8], 1);
        } else d[k] = -1;
    }
    __syncthreads();
    for (int b = threadIdx.x; b < NBMAX; b += 256) {
        int c = h[b];
        if (c) h[b] = atomicAdd(&cur[b], c);
    }
    __syncthreads();
#pragma unroll
    for (int k = 0; k < BIN_CH; ++k) {
        if (d[k] >= 0) {
            int pos = atomicAdd(&h[d[k] >> 8], 1);
            pr[pos] = ((unsigned)(d[k] & 255) << 24) | (unsigned)s[k];
        }
    }
}

__global__ __launch_bounds__(256) void k_bucket_fine(
    const unsigned* __restrict__ pairs, const int* __restrict__ base,
    int* __restrict__ row0, int* __restrict__ srcs0,
    int* __restrict__ row1, int* __restrict__ srcs1,
    int n, int nE, int nb)
{
    const unsigned* pr = pairs + (size_t)blockIdx.y * nE;
    const int* ba = base + blockIdx.y * 528;
    int* row = blockIdx.y ? row1 : row0;
    int* srcs = blockIdx.y ? srcs1 : srcs0;
    __shared__ int cnt[256], cur[256];
    int b = blockIdx.x;
    int t = threadIdx.x;
    int s0 = ba[b], s1 = ba[b + 1];
    cnt[t] = 0;
    __syncthreads();
    for (int i = s0 + t; i < s1; i += 256)
        atomicAdd(&cnt[pr[i] >> 24], 1);
    __syncthreads();
    int c = cnt[t];
    cur[t] = c;
    __syncthreads();
    for (int off = 1; off < 256; off <<= 1) {
        int x = (t >= off) ? cur[t - off] : 0;
        __syncthreads();
        cur[t] += x;
        __syncthreads();
    }
    int excl = cur[t] - c;
    __syncthreads();
    cur[t] = s0 + excl;
    int node = (b << 8) + t;
    if (node < n) row[node] = s0 + excl;
    if (b == nb - 1 && t == 0) row[n] = nE;
    __syncthreads();
    for (int i = s0 + t; i < s1; i += 256) {
        unsigned p = pr[i];
        int slot = atomicAdd(&cur[p >> 24], 1);
        srcs[slot] = (int)(p & 0xFFFFFFu);
    }
}

// ---------------- dense compute (branch via blockIdx.y + yoff) ----------------

struct TArgs { const void *x, *ws, *wn, *bias; float* acc; void* nbr; };

// acc = x @ w_self + bias (f32); nbr = x @ w_nbr (bf16x16 row, 32 B/node)
__global__ __launch_bounds__(256) void k_transform1(
    TArgs a0, TArgs a1, int n, int yoff, const int* __restrict__ flag)
{
    TArgs A = (blockIdx.y + yoff) ? a1 : a0;
    const int isf32 = *flag;
    __shared__ float Wl[F_IN][32];  // cols 0..15 = w_self, 16..31 = w_nbr
    for (int idx = threadIdx.x; idx < F_IN * 32; idx += 256) {
        int k = idx >> 5, j = idx & 31;
        Wl[k][j] = (j < 16) ? ldf(A.ws, isf32, k * 16 + j)
                            : ldf(A.wn, isf32, k * 16 + (j - 16));
    }
    __syncthreads();
    int node = blockIdx.x * 256 + threadIdx.x;
    if (node >= n) return;
    float acc[32];
#pragma unroll
    for (int j = 0; j < 16; ++j) acc[j] = ldf(A.bias, isf32, j);
#pragma unroll
    for (int j = 16; j < 32; ++j) acc[j] = 0.f;

    if (isf32) {
        const float4* xrow = (const float4*)((const float*)A.x + (size_t)node * F_IN);
        for (int kk = 0; kk < 32; ++kk) {
            float4 q = xrow[kk];
            float xs[4] = {q.x, q.y, q.z, q.w};
            int kbase = kk * 4;
#pragma unroll
            for (int h = 0; h < 4; ++h) {
                float xv = xs[h];
                const float* wrow = &Wl[kbase + h][0];
#pragma unroll
                for (int j = 0; j < 32; ++j) acc[j] += xv * wrow[j];
            }
        }
    } else {
        const uint4* xrow = (const uint4*)((const unsigned short*)A.x + (size_t)node * F_IN);
        for (int kk = 0; kk < 16; ++kk) {
            uint4 q = xrow[kk];
            float xs[8] = {bflo(q.x), bfhi(q.x), bflo(q.y), bfhi(q.y),
                           bflo(q.z), bfhi(q.z), bflo(q.w), bfhi(q.w)};
            int kbase = kk * 8;
#pragma unroll
            for (int h = 0; h < 8; ++h) {
                float xv = xs[h];
                const float* wrow = &Wl[kbase + h][0];
#pragma unroll
                for (int j = 0; j < 32; ++j) acc[j] += xv * wrow[j];
            }
        }
    }
    float4* a4 = (float4*)(A.acc + (size_t)node * 16);
#pragma unroll
    for (int t = 0; t < 4; ++t)
        a4[t] = make_float4(acc[4 * t], acc[4 * t + 1], acc[4 * t + 2], acc[4 * t + 3]);
    unsigned short* nrow = (unsigned short*)A.nbr + ((size_t)node << 4);
    *(uint4*)nrow = make_uint4(pack2bf(acc[16], acc[17]), pack2bf(acc[18], acc[19]),
                               pack2bf(acc[20], acc[21]), pack2bf(acc[22], acc[23]));
    *(uint4*)(nrow + 8) = make_uint4(pack2bf(acc[24], acc[25]), pack2bf(acc[26], acc[27]),
                                     pack2bf(acc[28], acc[29]), pack2bf(acc[30], acc[31]));
}

struct GArgs { const int *row, *srcs; const void* val; float* out; };

// out[node,0:16] (f32) = (selfmode ? out[node] : 0) + sum_{nbrs} bf16row val[s]
// 4 lanes/node; each lane covers 4 bf16 (8 B load). 8-deep unrolled pipeline.
__global__ __launch_bounds__(256) void k_gather16(
    GArgs g0, GArgs g1, int n, int selfmode, int yoff)
{
    GArgs G = (blockIdx.y + yoff) ? g1 : g0;
    int t = blockIdx.x * 256 + threadIdx.x;
    int node = t >> 2;
    if (node >= n) return;
    int c = (t & 3) << 2;   // element offset (4 bf16 per lane)
    const unsigned short* vb = (const unsigned short*)G.val;
    int rs = G.row[node], re = G.row[node + 1];
    float4 sum = make_float4(0.f, 0.f, 0.f, 0.f);
    if (selfmode) sum = *(const float4*)(G.out + ((size_t)node << 4) + c);
    int j = rs;
    for (; j + 8 <= re; j += 8) {
        int s[8];
        uint2 v[8];
#pragma unroll
        for (int u = 0; u < 8; ++u) s[u] = G.srcs[j + u];
#pragma unroll
        for (int u = 0; u < 8; ++u)
            v[u] = *(const uint2*)(vb + (((size_t)s[u]) << 4) + c);
#pragma unroll
        for (int u = 0; u < 8; ++u) {
            sum.x += bflo(v[u].x); sum.y += bfhi(v[u].x);
            sum.z += bflo(v[u].y); sum.w += bfhi(v[u].y);
        }
    }
    for (; j < re; ++j) {
        uint2 v = *(const uint2*)(vb + (((size_t)G.srcs[j]) << 4) + c);
        sum.x += bflo(v.x); sum.y += bfhi(v.x);
        sum.z += bflo(v.y); sum.w += bfhi(v.y);
    }
    *(float4*)(G.out + ((size_t)node << 4) + c) = sum;
}

struct L2aArgs { const float* h1; void* p1; const void *w2s, *b2; int colOff; };

// p = relu(h1); mol[:,off:off+50) = p @ w2s + b2; p1 (bf16 row) for gather 2
__global__ __launch_bounds__(256) void k_layer2a(
    L2aArgs a0, L2aArgs a1, float* __restrict__ mol, int n, int yoff,
    const int* __restrict__ flag)
{
    L2aArgs A = (blockIdx.y + yoff) ? a1 : a0;
    const int isf32 = *flag;
    __shared__ float Ws[16][50];
    __shared__ float Bs[50];
    for (int idx = threadIdx.x; idx < 800; idx += 256)
        Ws[idx / 50][idx % 50] = ldf(A.w2s, isf32, idx);
    if (threadIdx.x < 50) Bs[threadIdx.x] = ldf(A.b2, isf32, threadIdx.x);
    __syncthreads();
    int node = blockIdx.x * 256 + threadIdx.x;
    if (node >= n) return;
    float p[16];
    const float4* row = (const float4*)(A.h1 + (size_t)node * 16);
#pragma unroll
    for (int t = 0; t < 4; ++t) {
        float4 v = row[t];
        p[4 * t] = fmaxf(v.x, 0.f); p[4 * t + 1] = fmaxf(v.y, 0.f);
        p[4 * t + 2] = fmaxf(v.z, 0.f); p[4 * t + 3] = fmaxf(v.w, 0.f);
    }
    unsigned short* prow = (unsigned short*)A.p1 + ((size_t)node << 4);
    *(uint4*)prow = make_uint4(pack2bf(p[0], p[1]), pack2bf(p[2], p[3]),
                               pack2bf(p[4], p[5]), pack2bf(p[6], p[7]));
    *(uint4*)(prow + 8) = make_uint4(pack2bf(p[8], p[9]), pack2bf(p[10], p[11]),
                                     pack2bf(p[12], p[13]), pack2bf(p[14], p[15]));
    float acc[50];
#pragma unroll
    for (int j = 0; j < 50; ++j) acc[j] = Bs[j];
#pragma unroll
    for (int k = 0; k < 16; ++k) {
        float pv = p[k];
#pragma unroll
        for (int j = 0; j < 50; ++j) acc[j] += pv * Ws[k][j];
    }
    float* o = mol + (size_t)node * 100 + A.colOff;
#pragma unroll
    for (int j = 0; j < 50; ++j) o[j] = acc[j];
}

struct L2bArgs { const float* agg; const void* w2n; int colOff; };

// mol[:, colOff..colOff+50) += agg @ w2n
__global__ __launch_bounds__(256) void k_layer2b(
    L2bArgs a0, L2bArgs a1, float* __restrict__ mol, int n, int yoff,
    const int* __restrict__ flag)
{
    L2bArgs A = (blockIdx.y + yoff) ? a1 : a0;
    const int isf32 = *flag;
    __shared__ float Ws[16][50];
    for (int idx = threadIdx.x; idx < 800; idx += 256)
        Ws[idx / 50][idx % 50] = ldf(A.w2n, isf32, idx);
    __syncthreads();
    int node = blockIdx.x * 256 + threadIdx.x;
    if (node >= n) return;
    float g[16];
    const float4* grow = (const float4*)(A.agg + (size_t)node * 16);
#pragma unroll
    for (int t = 0; t < 4; ++t) {
        float4 v = grow[t];
        g[4 * t] = v.x; g[4 * t + 1] = v.y; g[4 * t + 2] = v.z; g[4 * t + 3] = v.w;
    }
    float* o = mol + (size_t)node * 100 + A.colOff;
    float acc[50];
#pragma unroll
    for (int j = 0; j < 50; ++j) acc[j] = o[j];
#pragma unroll
    for (int k = 0; k < 16; ++k) {
        float gv = g[k];
#pragma unroll
        for (int j = 0; j < 50; ++j) acc[j] += gv * Ws[k][j];
    }
#pragma unroll
    for (int j = 0; j < 50; ++j) o[j] = acc[j];
}

// head v3: 4 lanes per node. Lane q computes fp[q*15..q*15+15), partial h[10],
// __shfl_xor butterfly (masks 1,2) assembles full h; lane 0 adds action terms,
// relu, dot w_out, store. fp[15]/lane bounds register pressure structurally.
__global__ __launch_bounds__(256) void k_head(
    const float* __restrict__ mol, const void* __restrict__ action,
    const void* __restrict__ w_in, const void* __restrict__ b_in,
    const void* __restrict__ w_hid, const void* __restrict__ b_hid,
    const void* __restrict__ w_out, const void* __restrict__ b_out,
    void* __restrict__ out, int n, const int* __restrict__ flag)
{
    const int isf32 = *flag;
    __shared__ float Win[100 * 60];
    __shared__ float Whid[70 * 10];
    __shared__ float Bin[60], Bhid[10], Wout[10];
    __shared__ float Bout;
    for (int idx = threadIdx.x; idx < 6000; idx += 256) Win[idx] = ldf(w_in, isf32, idx);
    for (int idx = threadIdx.x; idx < 700; idx += 256) Whid[idx] = ldf(w_hid, isf32, idx);
    if (threadIdx.x < 60) Bin[threadIdx.x] = ldf(b_in, isf32, threadIdx.x);
    if (threadIdx.x < 10) {
        Bhid[threadIdx.x] = ldf(b_hid, isf32, threadIdx.x);
        Wout[threadIdx.x] = ldf(w_out, isf32, threadIdx.x);
    }
    if (threadIdx.x == 0) Bout = ldf(b_out, isf32, 0);
    __syncthreads();
    int t = blockIdx.x * 256 + threadIdx.x;
    int node = t >> 2;
    if (node >= n) return;
    const int q = threadIdx.x & 3;
    const int jo = q * 15;

    const float4* m4 = (const float4*)(mol + (size_t)node * 100);
    float fp[15];
#pragma unroll
    for (int j = 0; j < 15; ++j) fp[j] = Bin[jo + j];
    for (int kk = 0; kk < 25; ++kk) {
        float4 v = m4[kk];
        float xs[4] = {v.x, v.y, v.z, v.w};
#pragma unroll
        for (int hh = 0; hh < 4; ++hh) {
            float m = xs[hh];
            const float* w = &Win[(kk * 4 + hh) * 60 + jo];
#pragma unroll
            for (int j = 0; j < 15; ++j) fp[j] += m * w[j];
        }
    }
    float h[10];
#pragma unroll
    for (int j = 0; j < 10; ++j) h[j] = (q == 0) ? Bhid[j] : 0.f;
#pragma unroll
    for (int k = 0; k < 15; ++k) {
        float v = fmaxf(fp[k], 0.f);
        const float* w = &Whid[(jo + k) * 10];
#pragma unroll
        for (int j = 0; j < 10; ++j) h[j] += v * w[j];
    }
    // butterfly within the quad (lanes differ only in bits 0..1)
#pragma unroll
    for (int j = 0; j < 10; ++j) h[j] += __shfl_xor(h[j], 1);
#pragma unroll
    for (int j = 0; j < 10; ++j) h[j] += __shfl_xor(h[j], 2);

    if (q == 0) {
#pragma unroll
        for (int k = 0; k < 10; ++k) {
            float v = ldf(action, isf32, (size_t)node * 10 + k);
            const float* w = &Whid[(60 + k) * 10];
#pragma unroll
            for (int j = 0; j < 10; ++j) h[j] += v * w[j];
        }
        float o = Bout;
#pragma unroll
        for (int j = 0; j < 10; ++j) o += fmaxf(h[j], 0.f) * Wout[j];
        if (isf32) ((float*)out)[node] = o;
        else       ((unsigned short*)out)[node] = f2bf(o);
    }
}

extern "C" void kernel_launch(void* const* d_in, const int* in_sizes, int n_in,
                              void* d_out, int out_size, void* d_ws, size_t ws_size,
                              hipStream_t stream)
{
    const void* px   = d_in[0];
    const int*  pe   = (const int*)d_in[1];
    const void* lx   = d_in[2];
    const int*  le   = (const int*)d_in[3];
    const void* act  = d_in[4];
    const void* wp1s = d_in[5];
    const void* wp1n = d_in[6];
    const void* bp1  = d_in[7];
    const void* wp2s = d_in[8];
    const void* wp2n = d_in[9];
    const void* bp2  = d_in[10];
    const void* wl1s = d_in[11];
    const void* wl1n = d_in[12];
    const void* bl1  = d_in[13];
    const void* wl2s = d_in[14];
    const void* wl2n = d_in[15];
    const void* bl2  = d_in[16];
    const void* w_in  = d_in[17];
    const void* b_in  = d_in[18];
    const void* w_hid = d_in[19];
    const void* b_hid = d_in[20];
    const void* w_out = d_in[21];
    const void* b_out = d_in[22];

    const int N = in_sizes[0] / F_IN;
    const int E = in_sizes[1] / 2;
    const int NB = (N + 255) >> 8;

    // header: flag(64) | cnt(2*512) | base(2*528) | cursor(2*512) = 3200 ints
    int* flag    = (int*)d_ws;
    int* cnt     = flag + 64;
    int* base    = cnt + 2 * NBMAX;
    int* cursorB = base + 2 * 528;
    int* rowP    = flag + 3200;
    int* srcsP   = rowP + (N + 64);
    int* rowL    = srcsP + E;
    int* srcsL   = rowL + (N + 64);
    float* dense = (float*)(srcsL + E);
    unsigned* pairs = (unsigned*)dense;   // 2E uints; dead before dense writes

    size_t head_bytes  = (size_t)(3200 + 2 * (N + 64) + 2 * E) * 4;
    size_t need_fused  = head_bytes + (size_t)164 * N * 4;
    const bool fused = (ws_size >= need_fused);

    float *accP, *accL, *mol;
    void *n1P, *n1L;
    if (fused) {
        accP = dense;                       n1P = (void*)(accP + (size_t)N * 16);
        accL = (float*)n1P + (size_t)N * 16; n1L = (void*)(accL + (size_t)N * 16);
        mol  = (float*)n1L + (size_t)N * 16;
    } else {
        accP = accL = dense;
        n1P = n1L = (void*)(dense + (size_t)N * 16);
        mol  = dense + (size_t)N * 32;
    }

    const int nb = (N + 255) / 256;
    const int gb = (N * 4 + 255) / 256;
    const int bb = (E + 4095) / 4096;

    k_detect<<<1, 256, 0, stream>>>((const unsigned short*)px, 4096, flag);

    // ---- CSR build for both graphs (blockIdx.y = graph) ----
    k_zero<<<4, 256, 0, stream>>>(cnt, 2 * NBMAX);
    k_bucket_hist<<<dim3(512, 2), 256, 0, stream>>>(pe + E, le + E, cnt, E);
    k_bucket_scan<<<2, 512, 0, stream>>>(cnt, base, cursorB, NB);
    k_bucket_bin<<<dim3(bb, 2), 256, 0, stream>>>(pe, pe + E, le, le + E,
                                                  cursorB, pairs, E);
    k_bucket_fine<<<dim3(NB, 2), 256, 0, stream>>>(pairs, base, rowP, srcsP,
                                                   rowL, srcsL, N, E, NB);

    TArgs tP{px, wp1s, wp1n, bp1, accP, n1P};
    TArgs tL{lx, wl1s, wl1n, bl1, accL, n1L};
    GArgs g1P{rowP, srcsP, n1P, accP}, g1L{rowL, srcsL, n1L, accL};
    L2aArgs aP{accP, n1P, wp2s, bp2, 0}, aL{accL, n1L, wl2s, bl2, 50};
    L2bArgs bP{accP, wp2n, 0}, bL{accL, wl2n, 50};

    if (fused) {
        k_transform1<<<dim3(nb, 2), 256, 0, stream>>>(tP, tL, N, 0, flag);
        // gathers split per graph: 3.2 MB table fits one XCD L2
        k_gather16<<<gb, 256, 0, stream>>>(g1P, g1L, N, 1, 0);
        k_gather16<<<gb, 256, 0, stream>>>(g1P, g1L, N, 1, 1);
        k_layer2a<<<dim3(nb, 2), 256, 0, stream>>>(aP, aL, mol, N, 0, flag);
        k_gather16<<<gb, 256, 0, stream>>>(g1P, g1L, N, 0, 0);
        k_gather16<<<gb, 256, 0, stream>>>(g1P, g1L, N, 0, 1);
        k_layer2b<<<dim3(nb, 2), 256, 0, stream>>>(bP, bL, mol, N, 0, flag);
    } else {
        k_transform1<<<nb, 256, 0, stream>>>(tP, tL, N, 0, flag);
        k_gather16<<<gb, 256, 0, stream>>>(g1P, g1L, N, 1, 0);
        k_layer2a<<<nb, 256, 0, stream>>>(aP, aL, mol, N, 0, flag);
        k_gather16<<<gb, 256, 0, stream>>>(g1P, g1L, N, 0, 0);
        k_layer2b<<<nb, 256, 0, stream>>>(bP, bL, mol, N, 0, flag);

        k_transform1<<<nb, 256, 0, stream>>>(tP, tL, N, 1, flag);
        k_gather16<<<gb, 256, 0, stream>>>(g1P, g1L, N, 1, 1);
        k_layer2a<<<nb, 256, 0, stream>>>(aP, aL, mol, N, 1, flag);
        k_gather16<<<gb, 256, 0, stream>>>(g1P, g1L, N, 0, 1);
        k_layer2b<<<nb, 256, 0, stream>>>(bP, bL, mol, N, 1, flag);
    }

    // ---- head (4 lanes/node) ----
    k_head<<<gb, 256, 0, stream>>>(mol, act, w_in, b_in, w_hid, b_hid, w_out, b_out,
                                   d_out, N, flag);
}

// Round 8
// 609.244 us; speedup vs baseline: 4.8870x; 1.0742x over previous
//
#include <hip/hip_runtime.h>
#include <hip/hip_bf16.h>
#include <stdint.h>

// CriticGNN: two GraphConv branches + MLP head.
// R0: aggregate AFTER the 128->16 transform (segment_sum is linear).
// R1: runtime dtype detection (bf16 vs f32 device buffers).
// R2: CSR (counting sort by dst) + gather instead of f32 atomics.
// R3: two-level bucketed counting sort (LDS histograms, burst writes).
// R6: k_head 4 lanes/node + shfl butterfly (spill structurally bounded).
// R7: k_bucket_bin wrote 178 MB for 25.6 MB payload (partial-line evict/refetch
//     loop: 64 lanes -> 64 lines x 4 B). Fix: block-local LDS counting sort,
//     then coalesced LDS->global copy (each line written fully, once).

#define F_IN 128
#define NBMAX 512   // max coarse buckets (N <= 131072)
#define BIN_CH 16
#define BIN_EDGES (256 * BIN_CH)

__device__ __forceinline__ float bf2f(unsigned short u) {
    union { unsigned int i; float f; } v; v.i = ((unsigned int)u) << 16; return v.f;
}
__device__ __forceinline__ float bflo(unsigned int u) {
    union { unsigned int i; float f; } v; v.i = u << 16; return v.f;
}
__device__ __forceinline__ float bfhi(unsigned int u) {
    union { unsigned int i; float f; } v; v.i = u & 0xffff0000u; return v.f;
}
__device__ __forceinline__ unsigned short f2bf(float f) {
    union { float f; unsigned int i; } v; v.f = f;
    unsigned int u = v.i;
    unsigned int r = (u + 0x7fffu + ((u >> 16) & 1u)) >> 16;  // RNE
    return (unsigned short)r;
}
__device__ __forceinline__ unsigned pack2bf(float a, float b) {
    return (unsigned)f2bf(a) | ((unsigned)f2bf(b) << 16);
}
__device__ __forceinline__ float ldf(const void* p, int isf32, size_t i) {
    return isf32 ? ((const float*)p)[i] : bf2f(((const unsigned short*)p)[i]);
}

__global__ __launch_bounds__(256) void k_detect(
    const unsigned short* __restrict__ x, int nProbe, int* __restrict__ flag)
{
    __shared__ int cnt;
    if (threadIdx.x == 0) cnt = 0;
    __syncthreads();
    int bad = 0;
    for (int i = threadIdx.x; i < nProbe; i += 256) {
        unsigned e = (x[i] >> 7) & 0xFFu;
        if (e >= 140u) bad++;
    }
    atomicAdd(&cnt, bad);
    __syncthreads();
    if (threadIdx.x == 0) *flag = (cnt > nProbe / 16) ? 1 : 0;
}

// ---------------- bucketed CSR build (both graphs via blockIdx.y) ----------------

__global__ __launch_bounds__(256) void k_zero(int* __restrict__ p, int n) {
    int i = blockIdx.x * 256 + threadIdx.x;
    if (i < n) p[i] = 0;
}

__global__ __launch_bounds__(256) void k_bucket_hist(
    const int* __restrict__ ed0, const int* __restrict__ ed1,
    int* __restrict__ cnt, int nE)
{
    const int* ed = blockIdx.y ? ed1 : ed0;
    int* c = cnt + blockIdx.y * NBMAX;
    __shared__ int h[NBMAX];
    for (int i = threadIdx.x; i < NBMAX; i += 256) h[i] = 0;
    __syncthreads();
    int stride = gridDim.x * 256;
    for (int e = blockIdx.x * 256 + threadIdx.x; e < nE; e += stride)
        atomicAdd(&h[ed[e] >> 8], 1);
    __syncthreads();
    for (int i = threadIdx.x; i < NBMAX; i += 256)
        if (h[i]) atomicAdd(&c[i], h[i]);
}

__global__ __launch_bounds__(512) void k_bucket_scan(
    const int* __restrict__ cnt, int* __restrict__ base,
    int* __restrict__ cursor, int nb)
{
    const int* c = cnt + blockIdx.x * NBMAX;
    int* ba = base + blockIdx.x * 528;
    int* cu = cursor + blockIdx.x * NBMAX;
    __shared__ int sh[512];
    int t = threadIdx.x;
    int v = (t < nb) ? c[t] : 0;
    sh[t] = v;
    __syncthreads();
    for (int off = 1; off < 512; off <<= 1) {
        int x = (t >= off) ? sh[t - off] : 0;
        __syncthreads();
        sh[t] += x;
        __syncthreads();
    }
    int excl = sh[t] - v;
    if (t < nb) { ba[t] = excl; cu[t] = excl; }
    if (t == nb - 1) ba[nb] = excl + v;
}

// bin edges into bucket-contiguous packed array via block-local LDS sort:
// hist -> block scan -> global range reserve -> LDS scatter (grouped by
// bucket) -> coalesced LDS->global copy (slot i -> delta[bucket]+i).
__global__ __launch_bounds__(256) void k_bucket_bin(
    const int* __restrict__ es0, const int* __restrict__ ed0,
    const int* __restrict__ es1, const int* __restrict__ ed1,
    int* __restrict__ cursor, unsigned* __restrict__ pairs, int nE)
{
    const int* es = blockIdx.y ? es1 : es0;
    const int* ed = blockIdx.y ? ed1 : ed0;
    int* cur = cursor + blockIdx.y * NBMAX;
    unsigned* pr = pairs + (size_t)blockIdx.y * nE;

    __shared__ int h[NBMAX];              // hist, then delta (= gbase - lbase)
    __shared__ int lcur[NBMAX];           // block-local base, then LDS cursor
    __shared__ int sh[256];               // scan scratch
    __shared__ unsigned stage[BIN_EDGES]; // payload grouped by bucket
    __shared__ unsigned short stageB[BIN_EDGES]; // bucket id per slot

    for (int i = threadIdx.x; i < NBMAX; i += 256) h[i] = 0;
    __syncthreads();
    int e0 = blockIdx.x * BIN_EDGES;
    int s[BIN_CH], d[BIN_CH];
#pragma unroll
    for (int k = 0; k < BIN_CH; ++k) {
        int e = e0 + k * 256 + threadIdx.x;
        if (e < nE) {
            s[k] = es[e]; d[k] = ed[e];
            atomicAdd(&h[d[k] >> 8], 1);
        } else d[k] = -1;
    }
    __syncthreads();
    // block-exclusive scan of h[0..512) -> lcur (2 elems/thread)
    {
        int t = threadIdx.x;
        int a = h[2 * t], b2 = h[2 * t + 1];
        sh[t] = a + b2;
        __syncthreads();
        for (int off = 1; off < 256; off <<= 1) {
            int x = (t >= off) ? sh[t - off] : 0;
            __syncthreads();
            sh[t] += x;
            __syncthreads();
        }
        int excl = sh[t] - (a + b2);
        lcur[2 * t] = excl;
        lcur[2 * t + 1] = excl + a;
    }
    __syncthreads();
    // reserve global ranges; h becomes delta
    for (int b = threadIdx.x; b < NBMAX; b += 256) {
        int c = h[b];
        if (c) {
            int g = atomicAdd(&cur[b], c);
            h[b] = g - lcur[b];
        }
    }
    __syncthreads();
    // scatter into LDS staging, grouped by bucket
#pragma unroll
    for (int k = 0; k < BIN_CH; ++k) {
        if (d[k] >= 0) {
            int b = d[k] >> 8;
            int pos = atomicAdd(&lcur[b], 1);
            stage[pos] = ((unsigned)(d[k] & 255) << 24) | (unsigned)s[k];
            stageB[pos] = (unsigned short)b;
        }
    }
    __syncthreads();
    // coalesced copy out: consecutive slots -> consecutive global addrs
    int total = nE - e0; if (total > BIN_EDGES) total = BIN_EDGES;
    for (int i = threadIdx.x; i < total; i += 256)
        pr[h[stageB[i]] + i] = stage[i];
}

__global__ __launch_bounds__(256) void k_bucket_fine(
    const unsigned* __restrict__ pairs, const int* __restrict__ base,
    int* __restrict__ row0, int* __restrict__ srcs0,
    int* __restrict__ row1, int* __restrict__ srcs1,
    int n, int nE, int nb)
{
    const unsigned* pr = pairs + (size_t)blockIdx.y * nE;
    const int* ba = base + blockIdx.y * 528;
    int* row = blockIdx.y ? row1 : row0;
    int* srcs = blockIdx.y ? srcs1 : srcs0;
    __shared__ int cnt[256], cur[256];
    int b = blockIdx.x;
    int t = threadIdx.x;
    int s0 = ba[b], s1 = ba[b + 1];
    cnt[t] = 0;
    __syncthreads();
    for (int i = s0 + t; i < s1; i += 256)
        atomicAdd(&cnt[pr[i] >> 24], 1);
    __syncthreads();
    int c = cnt[t];
    cur[t] = c;
    __syncthreads();
    for (int off = 1; off < 256; off <<= 1) {
        int x = (t >= off) ? cur[t - off] : 0;
        __syncthreads();
        cur[t] += x;
        __syncthreads();
    }
    int excl = cur[t] - c;
    __syncthreads();
    cur[t] = s0 + excl;
    int node = (b << 8) + t;
    if (node < n) row[node] = s0 + excl;
    if (b == nb - 1 && t == 0) row[n] = nE;
    __syncthreads();
    for (int i = s0 + t; i < s1; i += 256) {
        unsigned p = pr[i];
        int slot = atomicAdd(&cur[p >> 24], 1);
        srcs[slot] = (int)(p & 0xFFFFFFu);
    }
}

// ---------------- dense compute (branch via blockIdx.y + yoff) ----------------

struct TArgs { const void *x, *ws, *wn, *bias; float* acc; void* nbr; };

// acc = x @ w_self + bias (f32); nbr = x @ w_nbr (bf16x16 row, 32 B/node)
__global__ __launch_bounds__(256) void k_transform1(
    TArgs a0, TArgs a1, int n, int yoff, const int* __restrict__ flag)
{
    TArgs A = (blockIdx.y + yoff) ? a1 : a0;
    const int isf32 = *flag;
    __shared__ float Wl[F_IN][32];  // cols 0..15 = w_self, 16..31 = w_nbr
    for (int idx = threadIdx.x; idx < F_IN * 32; idx += 256) {
        int k = idx >> 5, j = idx & 31;
        Wl[k][j] = (j < 16) ? ldf(A.ws, isf32, k * 16 + j)
                            : ldf(A.wn, isf32, k * 16 + (j - 16));
    }
    __syncthreads();
    int node = blockIdx.x * 256 + threadIdx.x;
    if (node >= n) return;
    float acc[32];
#pragma unroll
    for (int j = 0; j < 16; ++j) acc[j] = ldf(A.bias, isf32, j);
#pragma unroll
    for (int j = 16; j < 32; ++j) acc[j] = 0.f;

    if (isf32) {
        const float4* xrow = (const float4*)((const float*)A.x + (size_t)node * F_IN);
        for (int kk = 0; kk < 32; ++kk) {
            float4 q = xrow[kk];
            float xs[4] = {q.x, q.y, q.z, q.w};
            int kbase = kk * 4;
#pragma unroll
            for (int h = 0; h < 4; ++h) {
                float xv = xs[h];
                const float* wrow = &Wl[kbase + h][0];
#pragma unroll
                for (int j = 0; j < 32; ++j) acc[j] += xv * wrow[j];
            }
        }
    } else {
        const uint4* xrow = (const uint4*)((const unsigned short*)A.x + (size_t)node * F_IN);
        for (int kk = 0; kk < 16; ++kk) {
            uint4 q = xrow[kk];
            float xs[8] = {bflo(q.x), bfhi(q.x), bflo(q.y), bfhi(q.y),
                           bflo(q.z), bfhi(q.z), bflo(q.w), bfhi(q.w)};
            int kbase = kk * 8;
#pragma unroll
            for (int h = 0; h < 8; ++h) {
                float xv = xs[h];
                const float* wrow = &Wl[kbase + h][0];
#pragma unroll
                for (int j = 0; j < 32; ++j) acc[j] += xv * wrow[j];
            }
        }
    }
    float4* a4 = (float4*)(A.acc + (size_t)node * 16);
#pragma unroll
    for (int t = 0; t < 4; ++t)
        a4[t] = make_float4(acc[4 * t], acc[4 * t + 1], acc[4 * t + 2], acc[4 * t + 3]);
    unsigned short* nrow = (unsigned short*)A.nbr + ((size_t)node << 4);
    *(uint4*)nrow = make_uint4(pack2bf(acc[16], acc[17]), pack2bf(acc[18], acc[19]),
                               pack2bf(acc[20], acc[21]), pack2bf(acc[22], acc[23]));
    *(uint4*)(nrow + 8) = make_uint4(pack2bf(acc[24], acc[25]), pack2bf(acc[26], acc[27]),
                                     pack2bf(acc[28], acc[29]), pack2bf(acc[30], acc[31]));
}

struct GArgs { const int *row, *srcs; const void* val; float* out; };

// out[node,0:16] (f32) = (selfmode ? out[node] : 0) + sum_{nbrs} bf16row val[s]
__global__ __launch_bounds__(256) void k_gather16(
    GArgs g0, GArgs g1, int n, int selfmode, int yoff)
{
    GArgs G = (blockIdx.y + yoff) ? g1 : g0;
    int t = blockIdx.x * 256 + threadIdx.x;
    int node = t >> 2;
    if (node >= n) return;
    int c = (t & 3) << 2;   // element offset (4 bf16 per lane)
    const unsigned short* vb = (const unsigned short*)G.val;
    int rs = G.row[node], re = G.row[node + 1];
    float4 sum = make_float4(0.f, 0.f, 0.f, 0.f);
    if (selfmode) sum = *(const float4*)(G.out + ((size_t)node << 4) + c);
    int j = rs;
    for (; j + 8 <= re; j += 8) {
        int s[8];
        uint2 v[8];
#pragma unroll
        for (int u = 0; u < 8; ++u) s[u] = G.srcs[j + u];
#pragma unroll
        for (int u = 0; u < 8; ++u)
            v[u] = *(const uint2*)(vb + (((size_t)s[u]) << 4) + c);
#pragma unroll
        for (int u = 0; u < 8; ++u) {
            sum.x += bflo(v[u].x); sum.y += bfhi(v[u].x);
            sum.z += bflo(v[u].y); sum.w += bfhi(v[u].y);
        }
    }
    for (; j < re; ++j) {
        uint2 v = *(const uint2*)(vb + (((size_t)G.srcs[j]) << 4) + c);
        sum.x += bflo(v.x); sum.y += bfhi(v.x);
        sum.z += bflo(v.y); sum.w += bfhi(v.y);
    }
    *(float4*)(G.out + ((size_t)node << 4) + c) = sum;
}

struct L2aArgs { const float* h1; void* p1; const void *w2s, *b2; int colOff; };

// p = relu(h1); mol[:,off:off+50) = p @ w2s + b2; p1 (bf16 row) for gather 2
__global__ __launch_bounds__(256) void k_layer2a(
    L2aArgs a0, L2aArgs a1, float* __restrict__ mol, int n, int yoff,
    const int* __restrict__ flag)
{
    L2aArgs A = (blockIdx.y + yoff) ? a1 : a0;
    const int isf32 = *flag;
    __shared__ float Ws[16][50];
    __shared__ float Bs[50];
    for (int idx = threadIdx.x; idx < 800; idx += 256)
        Ws[idx / 50][idx % 50] = ldf(A.w2s, isf32, idx);
    if (threadIdx.x < 50) Bs[threadIdx.x] = ldf(A.b2, isf32, threadIdx.x);
    __syncthreads();
    int node = blockIdx.x * 256 + threadIdx.x;
    if (node >= n) return;
    float p[16];
    const float4* row = (const float4*)(A.h1 + (size_t)node * 16);
#pragma unroll
    for (int t = 0; t < 4; ++t) {
        float4 v = row[t];
        p[4 * t] = fmaxf(v.x, 0.f); p[4 * t + 1] = fmaxf(v.y, 0.f);
        p[4 * t + 2] = fmaxf(v.z, 0.f); p[4 * t + 3] = fmaxf(v.w, 0.f);
    }
    unsigned short* prow = (unsigned short*)A.p1 + ((size_t)node << 4);
    *(uint4*)prow = make_uint4(pack2bf(p[0], p[1]), pack2bf(p[2], p[3]),
                               pack2bf(p[4], p[5]), pack2bf(p[6], p[7]));
    *(uint4*)(prow + 8) = make_uint4(pack2bf(p[8], p[9]), pack2bf(p[10], p[11]),
                                     pack2bf(p[12], p[13]), pack2bf(p[14], p[15]));
    float acc[50];
#pragma unroll
    for (int j = 0; j < 50; ++j) acc[j] = Bs[j];
#pragma unroll
    for (int k = 0; k < 16; ++k) {
        float pv = p[k];
#pragma unroll
        for (int j = 0; j < 50; ++j) acc[j] += pv * Ws[k][j];
    }
    float* o = mol + (size_t)node * 100 + A.colOff;
#pragma unroll
    for (int j = 0; j < 50; ++j) o[j] = acc[j];
}

struct L2bArgs { const float* agg; const void* w2n; int colOff; };

// mol[:, colOff..colOff+50) += agg @ w2n
__global__ __launch_bounds__(256) void k_layer2b(
    L2bArgs a0, L2bArgs a1, float* __restrict__ mol, int n, int yoff,
    const int* __restrict__ flag)
{
    L2bArgs A = (blockIdx.y + yoff) ? a1 : a0;
    const int isf32 = *flag;
    __shared__ float Ws[16][50];
    for (int idx = threadIdx.x; idx < 800; idx += 256)
        Ws[idx / 50][idx % 50] = ldf(A.w2n, isf32, idx);
    __syncthreads();
    int node = blockIdx.x * 256 + threadIdx.x;
    if (node >= n) return;
    float g[16];
    const float4* grow = (const float4*)(A.agg + (size_t)node * 16);
#pragma unroll
    for (int t = 0; t < 4; ++t) {
        float4 v = grow[t];
        g[4 * t] = v.x; g[4 * t + 1] = v.y; g[4 * t + 2] = v.z; g[4 * t + 3] = v.w;
    }
    float* o = mol + (size_t)node * 100 + A.colOff;
    float acc[50];
#pragma unroll
    for (int j = 0; j < 50; ++j) acc[j] = o[j];
#pragma unroll
    for (int k = 0; k < 16; ++k) {
        float gv = g[k];
#pragma unroll
        for (int j = 0; j < 50; ++j) acc[j] += gv * Ws[k][j];
    }
#pragma unroll
    for (int j = 0; j < 50; ++j) o[j] = acc[j];
}

// head: 4 lanes/node, fp[15]/lane, __shfl_xor butterfly for h[10]
__global__ __launch_bounds__(256) void k_head(
    const float* __restrict__ mol, const void* __restrict__ action,
    const void* __restrict__ w_in, const void* __restrict__ b_in,
    const void* __restrict__ w_hid, const void* __restrict__ b_hid,
    const void* __restrict__ w_out, const void* __restrict__ b_out,
    void* __restrict__ out, int n, const int* __restrict__ flag)
{
    const int isf32 = *flag;
    __shared__ float Win[100 * 60];
    __shared__ float Whid[70 * 10];
    __shared__ float Bin[60], Bhid[10], Wout[10];
    __shared__ float Bout;
    for (int idx = threadIdx.x; idx < 6000; idx += 256) Win[idx] = ldf(w_in, isf32, idx);
    for (int idx = threadIdx.x; idx < 700; idx += 256) Whid[idx] = ldf(w_hid, isf32, idx);
    if (threadIdx.x < 60) Bin[threadIdx.x] = ldf(b_in, isf32, threadIdx.x);
    if (threadIdx.x < 10) {
        Bhid[threadIdx.x] = ldf(b_hid, isf32, threadIdx.x);
        Wout[threadIdx.x] = ldf(w_out, isf32, threadIdx.x);
    }
    if (threadIdx.x == 0) Bout = ldf(b_out, isf32, 0);
    __syncthreads();
    int t = blockIdx.x * 256 + threadIdx.x;
    int node = t >> 2;
    if (node >= n) return;
    const int q = threadIdx.x & 3;
    const int jo = q * 15;

    const float4* m4 = (const float4*)(mol + (size_t)node * 100);
    float fp[15];
#pragma unroll
    for (int j = 0; j < 15; ++j) fp[j] = Bin[jo + j];
    for (int kk = 0; kk < 25; ++kk) {
        float4 v = m4[kk];
        float xs[4] = {v.x, v.y, v.z, v.w};
#pragma unroll
        for (int hh = 0; hh < 4; ++hh) {
            float m = xs[hh];
            const float* w = &Win[(kk * 4 + hh) * 60 + jo];
#pragma unroll
            for (int j = 0; j < 15; ++j) fp[j] += m * w[j];
        }
    }
    float h[10];
#pragma unroll
    for (int j = 0; j < 10; ++j) h[j] = (q == 0) ? Bhid[j] : 0.f;
#pragma unroll
    for (int k = 0; k < 15; ++k) {
        float v = fmaxf(fp[k], 0.f);
        const float* w = &Whid[(jo + k) * 10];
#pragma unroll
        for (int j = 0; j < 10; ++j) h[j] += v * w[j];
    }
#pragma unroll
    for (int j = 0; j < 10; ++j) h[j] += __shfl_xor(h[j], 1);
#pragma unroll
    for (int j = 0; j < 10; ++j) h[j] += __shfl_xor(h[j], 2);

    if (q == 0) {
#pragma unroll
        for (int k = 0; k < 10; ++k) {
            float v = ldf(action, isf32, (size_t)node * 10 + k);
            const float* w = &Whid[(60 + k) * 10];
#pragma unroll
            for (int j = 0; j < 10; ++j) h[j] += v * w[j];
        }
        float o = Bout;
#pragma unroll
        for (int j = 0; j < 10; ++j) o += fmaxf(h[j], 0.f) * Wout[j];
        if (isf32) ((float*)out)[node] = o;
        else       ((unsigned short*)out)[node] = f2bf(o);
    }
}

extern "C" void kernel_launch(void* const* d_in, const int* in_sizes, int n_in,
                              void* d_out, int out_size, void* d_ws, size_t ws_size,
                              hipStream_t stream)
{
    const void* px   = d_in[0];
    const int*  pe   = (const int*)d_in[1];
    const void* lx   = d_in[2];
    const int*  le   = (const int*)d_in[3];
    const void* act  = d_in[4];
    const void* wp1s = d_in[5];
    const void* wp1n = d_in[6];
    const void* bp1  = d_in[7];
    const void* wp2s = d_in[8];
    const void* wp2n = d_in[9];
    const void* bp2  = d_in[10];
    const void* wl1s = d_in[11];
    const void* wl1n = d_in[12];
    const void* bl1  = d_in[13];
    const void* wl2s = d_in[14];
    const void* wl2n = d_in[15];
    const void* bl2  = d_in[16];
    const void* w_in  = d_in[17];
    const void* b_in  = d_in[18];
    const void* w_hid = d_in[19];
    const void* b_hid = d_in[20];
    const void* w_out = d_in[21];
    const void* b_out = d_in[22];

    const int N = in_sizes[0] / F_IN;
    const int E = in_sizes[1] / 2;
    const int NB = (N + 255) >> 8;

    // header: flag(64) | cnt(2*512) | base(2*528) | cursor(2*512) = 3200 ints
    int* flag    = (int*)d_ws;
    int* cnt     = flag + 64;
    int* base    = cnt + 2 * NBMAX;
    int* cursorB = base + 2 * 528;
    int* rowP    = flag + 3200;
    int* srcsP   = rowP + (N + 64);
    int* rowL    = srcsP + E;
    int* srcsL   = rowL + (N + 64);
    float* dense = (float*)(srcsL + E);
    unsigned* pairs = (unsigned*)dense;   // 2E uints; dead before dense writes

    size_t head_bytes  = (size_t)(3200 + 2 * (N + 64) + 2 * E) * 4;
    size_t need_fused  = head_bytes + (size_t)164 * N * 4;
    const bool fused = (ws_size >= need_fused);

    float *accP, *accL, *mol;
    void *n1P, *n1L;
    if (fused) {
        accP = dense;                       n1P = (void*)(accP + (size_t)N * 16);
        accL = (float*)n1P + (size_t)N * 16; n1L = (void*)(accL + (size_t)N * 16);
        mol  = (float*)n1L + (size_t)N * 16;
    } else {
        accP = accL = dense;
        n1P = n1L = (void*)(dense + (size_t)N * 16);
        mol  = dense + (size_t)N * 32;
    }

    const int nb = (N + 255) / 256;
    const int gb = (N * 4 + 255) / 256;
    const int bb = (E + BIN_EDGES - 1) / BIN_EDGES;

    k_detect<<<1, 256, 0, stream>>>((const unsigned short*)px, 4096, flag);

    // ---- CSR build for both graphs (blockIdx.y = graph) ----
    k_zero<<<4, 256, 0, stream>>>(cnt, 2 * NBMAX);
    k_bucket_hist<<<dim3(512, 2), 256, 0, stream>>>(pe + E, le + E, cnt, E);
    k_bucket_scan<<<2, 512, 0, stream>>>(cnt, base, cursorB, NB);
    k_bucket_bin<<<dim3(bb, 2), 256, 0, stream>>>(pe, pe + E, le, le + E,
                                                  cursorB, pairs, E);
    k_bucket_fine<<<dim3(NB, 2), 256, 0, stream>>>(pairs, base, rowP, srcsP,
                                                   rowL, srcsL, N, E, NB);

    TArgs tP{px, wp1s, wp1n, bp1, accP, n1P};
    TArgs tL{lx, wl1s, wl1n, bl1, accL, n1L};
    GArgs g1P{rowP, srcsP, n1P, accP}, g1L{rowL, srcsL, n1L, accL};
    L2aArgs aP{accP, n1P, wp2s, bp2, 0}, aL{accL, n1L, wl2s, bl2, 50};
    L2bArgs bP{accP, wp2n, 0}, bL{accL, wl2n, 50};

    if (fused) {
        k_transform1<<<dim3(nb, 2), 256, 0, stream>>>(tP, tL, N, 0, flag);
        // gathers split per graph: 3.2 MB table fits one XCD L2
        k_gather16<<<gb, 256, 0, stream>>>(g1P, g1L, N, 1, 0);
        k_gather16<<<gb, 256, 0, stream>>>(g1P, g1L, N, 1, 1);
        k_layer2a<<<dim3(nb, 2), 256, 0, stream>>>(aP, aL, mol, N, 0, flag);
        k_gather16<<<gb, 256, 0, stream>>>(g1P, g1L, N, 0, 0);
        k_gather16<<<gb, 256, 0, stream>>>(g1P, g1L, N, 0, 1);
        k_layer2b<<<dim3(nb, 2), 256, 0, stream>>>(bP, bL, mol, N, 0, flag);
    } else {
        k_transform1<<<nb, 256, 0, stream>>>(tP, tL, N, 0, flag);
        k_gather16<<<gb, 256, 0, stream>>>(g1P, g1L, N, 1, 0);
        k_layer2a<<<nb, 256, 0, stream>>>(aP, aL, mol, N, 0, flag);
        k_gather16<<<gb, 256, 0, stream>>>(g1P, g1L, N, 0, 0);
        k_layer2b<<<nb, 256, 0, stream>>>(bP, bL, mol, N, 0, flag);

        k_transform1<<<nb, 256, 0, stream>>>(tP, tL, N, 1, flag);
        k_gather16<<<gb, 256, 0, stream>>>(g1P, g1L, N, 1, 1);
        k_layer2a<<<nb, 256, 0, stream>>>(aP, aL, mol, N, 1, flag);
        k_gather16<<<gb, 256, 0, stream>>>(g1P, g1L, N, 0, 1);
        k_layer2b<<<nb, 256, 0, stream>>>(bP, bL, mol, N, 1, flag);
    }

    // ---- head (4 lanes/node) ----
    k_head<<<gb, 256, 0, stream>>>(mol, act, w_in, b_in, w_hid, b_hid, w_out, b_out,
                                   d_out, N, flag);
}